// Round 1
// baseline (1369.356 us; speedup 1.0000x reference)
//
#include <hip/hip_runtime.h>
#include <math.h>

#define N_NODES 32768
#define N_EDGES 524288
#define DIM     128

static constexpr size_t NM = (size_t)N_NODES * DIM;   // 4194304 floats

// ---------------------------------------------------------------------------
// Tiled SGEMM: C[M,Nout] = act(A[M,K] * W[Nout,K]^T + bias)
// 64x64 tile per block, 256 threads, 4x4 per thread, K-tile 16.
// ACT: 0 = none, 1 = relu
// ---------------------------------------------------------------------------
template<int ACT>
__global__ __launch_bounds__(256)
void sgemm_kernel(const float* __restrict__ A, const float* __restrict__ W,
                  const float* __restrict__ bias, float* __restrict__ C,
                  int K, int Nout)
{
    __shared__ float As[16][68];   // [kk][m], padded row (272B, 16B-aligned)
    __shared__ float Bs[16][68];   // [kk][n]

    const int tx = threadIdx.x & 15;
    const int ty = threadIdx.x >> 4;
    const int bm = blockIdx.y * 64;
    const int bn = blockIdx.x * 64;

    float acc[4][4] = {};

    for (int k0 = 0; k0 < K; k0 += 16) {
        __syncthreads();
        #pragma unroll
        for (int i = 0; i < 4; ++i) {
            int idx = threadIdx.x + i * 256;
            int kk  = idx & 15;
            int m   = idx >> 4;
            As[kk][m] = A[(size_t)(bm + m) * K + k0 + kk];
            Bs[kk][m] = W[(size_t)(bn + m) * K + k0 + kk];
        }
        __syncthreads();
        #pragma unroll
        for (int kk = 0; kk < 16; ++kk) {
            float4 a4 = *(const float4*)&As[kk][ty * 4];
            float4 b4 = *(const float4*)&Bs[kk][tx * 4];
            float av[4] = {a4.x, a4.y, a4.z, a4.w};
            float bv[4] = {b4.x, b4.y, b4.z, b4.w};
            #pragma unroll
            for (int r = 0; r < 4; ++r)
                #pragma unroll
                for (int c = 0; c < 4; ++c)
                    acc[r][c] += av[r] * bv[c];
        }
    }

    #pragma unroll
    for (int r = 0; r < 4; ++r) {
        int row = bm + ty * 4 + r;
        int col = bn + tx * 4;
        float4 o;
        float* po = (float*)&o;
        #pragma unroll
        for (int c = 0; c < 4; ++c) {
            float v = acc[r][c] + bias[col + c];
            if (ACT == 1) v = fmaxf(v, 0.0f);
            po[c] = v;
        }
        *(float4*)&C[(size_t)row * Nout + col] = o;
    }
}

// ---------------------------------------------------------------------------
// Edge kernel: msg = sigmoid(k[dst] + q[src]) * v[src]; atomicAdd into agg[dst]
// agg is pre-initialized with the skip projection. One thread per 4 floats.
// ---------------------------------------------------------------------------
__global__ __launch_bounds__(256)
void edge_kernel(const float* __restrict__ kf, const float* __restrict__ qf,
                 const float* __restrict__ vf, const int* __restrict__ ei,
                 float* __restrict__ agg)
{
    int t = blockIdx.x * 256 + threadIdx.x;   // 0 .. E*32-1
    int e = t >> 5;
    int c = (t & 31) * 4;
    int s = ei[e];            // src = edge_index[0][e]
    int d = ei[N_EDGES + e];  // dst = edge_index[1][e]

    float4 kk = *(const float4*)(kf + (size_t)d * DIM + c);
    float4 qq = *(const float4*)(qf + (size_t)s * DIM + c);
    float4 vv = *(const float4*)(vf + (size_t)s * DIM + c);

    float m0 = vv.x / (1.0f + __expf(-(kk.x + qq.x)));
    float m1 = vv.y / (1.0f + __expf(-(kk.y + qq.y)));
    float m2 = vv.z / (1.0f + __expf(-(kk.z + qq.z)));
    float m3 = vv.w / (1.0f + __expf(-(kk.w + qq.w)));

    float* dst = agg + (size_t)d * DIM + c;
    atomicAdd(dst + 0, m0);
    atomicAdd(dst + 1, m1);
    atomicAdd(dst + 2, m2);
    atomicAdd(dst + 3, m3);
}

// ---------------------------------------------------------------------------
// Flash attention over equal-size graphs. One thread = one query row.
// qkv layout: [N, 384] = [q(128) | k(128) | v(128)], head slice = h*32.
// Block = 256 threads = 256 q-rows of one (b,h); K/V staged in LDS chunks.
// ---------------------------------------------------------------------------
__global__ __launch_bounds__(256)
void attn_kernel(const float* __restrict__ qkv, float* __restrict__ ctx)
{
    const int blk = blockIdx.x;          // B*H*2 = 512 blocks
    const int qt  = blk & 1;
    const int h   = (blk >> 1) & 3;
    const int b   = blk >> 3;

    const int qrow = qt * 256 + threadIdx.x;
    const int node = b * 512 + qrow;
    const float scale = 0.17677669529663687f;   // 1/sqrt(32)

    float qreg[32];
    {
        const float* qp = qkv + (size_t)node * 384 + h * 32;
        #pragma unroll
        for (int dd = 0; dd < 8; ++dd) {
            float4 q4 = *(const float4*)(qp + dd * 4);
            qreg[dd*4+0] = q4.x * scale; qreg[dd*4+1] = q4.y * scale;
            qreg[dd*4+2] = q4.z * scale; qreg[dd*4+3] = q4.w * scale;
        }
    }

    float m = -1e30f, l = 0.0f;
    float acc[32] = {};

    __shared__ float Ks[128][32];
    __shared__ float Vs[128][32];

    for (int kc = 0; kc < 4; ++kc) {
        __syncthreads();
        #pragma unroll
        for (int i = 0; i < 4; ++i) {
            int idx = threadIdx.x + i * 256;      // 0..1023
            int row = idx >> 3;
            int cc  = (idx & 7) * 4;
            int knode = b * 512 + kc * 128 + row;
            const float* base = qkv + (size_t)knode * 384 + h * 32;
            *(float4*)&Ks[row][cc] = *(const float4*)(base + 128 + cc);
            *(float4*)&Vs[row][cc] = *(const float4*)(base + 256 + cc);
        }
        __syncthreads();

        for (int j = 0; j < 128; ++j) {
            float sc = 0.0f;
            #pragma unroll
            for (int dd = 0; dd < 8; ++dd) {
                float4 k4 = *(const float4*)&Ks[j][dd * 4];   // broadcast read
                sc += qreg[dd*4+0]*k4.x + qreg[dd*4+1]*k4.y
                    + qreg[dd*4+2]*k4.z + qreg[dd*4+3]*k4.w;
            }
            if (sc > m) {
                float corr = __expf(m - sc);
                l *= corr;
                #pragma unroll
                for (int dd = 0; dd < 32; ++dd) acc[dd] *= corr;
                m = sc;
            }
            float p = __expf(sc - m);
            l += p;
            #pragma unroll
            for (int dd = 0; dd < 8; ++dd) {
                float4 v4 = *(const float4*)&Vs[j][dd * 4];   // broadcast read
                acc[dd*4+0] += p * v4.x; acc[dd*4+1] += p * v4.y;
                acc[dd*4+2] += p * v4.z; acc[dd*4+3] += p * v4.w;
            }
        }
    }

    float inv = 1.0f / l;
    float* op = ctx + (size_t)node * DIM + h * 32;
    #pragma unroll
    for (int dd = 0; dd < 8; ++dd) {
        float4 o;
        o.x = acc[dd*4+0]*inv; o.y = acc[dd*4+1]*inv;
        o.z = acc[dd*4+2]*inv; o.w = acc[dd*4+3]*inv;
        *(float4*)(op + dd * 4) = o;
    }
}

// ---------------------------------------------------------------------------
// Elementwise: out = (a + b) * (g[c]/sqrt(1+eps)) + beta[c]
// ---------------------------------------------------------------------------
__global__ __launch_bounds__(256)
void bn_add_kernel(const float* __restrict__ a, const float* __restrict__ b,
                   const float* __restrict__ g, const float* __restrict__ beta,
                   float* __restrict__ out)
{
    int t = blockIdx.x * 256 + threadIdx.x;   // NM/4 threads
    int c = (t & 31) * 4;
    const float rs = 0.9999950000374998f;     // 1/sqrt(1+1e-5)
    float4 av = *(const float4*)(a + (size_t)t * 4);
    float4 bv = *(const float4*)(b + (size_t)t * 4);
    float4 gv = *(const float4*)(g + c);
    float4 bt = *(const float4*)(beta + c);
    float4 o;
    o.x = (av.x + bv.x) * (gv.x * rs) + bt.x;
    o.y = (av.y + bv.y) * (gv.y * rs) + bt.y;
    o.z = (av.z + bv.z) * (gv.z * rs) + bt.z;
    o.w = (av.w + bv.w) * (gv.w * rs) + bt.w;
    *(float4*)(out + (size_t)t * 4) = o;
}

// h = hlocal + bn(hin1 + hattn)
__global__ __launch_bounds__(256)
void combine_kernel(const float* __restrict__ hlocal, const float* __restrict__ hin1,
                    const float* __restrict__ hattn, const float* __restrict__ g,
                    const float* __restrict__ beta, float* __restrict__ out)
{
    int t = blockIdx.x * 256 + threadIdx.x;
    int c = (t & 31) * 4;
    const float rs = 0.9999950000374998f;
    float4 hl = *(const float4*)(hlocal + (size_t)t * 4);
    float4 hi = *(const float4*)(hin1   + (size_t)t * 4);
    float4 ha = *(const float4*)(hattn  + (size_t)t * 4);
    float4 gv = *(const float4*)(g + c);
    float4 bt = *(const float4*)(beta + c);
    float4 o;
    o.x = hl.x + (hi.x + ha.x) * (gv.x * rs) + bt.x;
    o.y = hl.y + (hi.y + ha.y) * (gv.y * rs) + bt.y;
    o.z = hl.z + (hi.z + ha.z) * (gv.z * rs) + bt.z;
    o.w = hl.w + (hi.w + ha.w) * (gv.w * rs) + bt.w;
    *(float4*)(out + (size_t)t * 4) = o;
}

// ---------------------------------------------------------------------------
extern "C" void kernel_launch(void* const* d_in, const int* in_sizes, int n_in,
                              void* d_out, int out_size, void* d_ws, size_t ws_size,
                              hipStream_t stream)
{
    (void)in_sizes; (void)n_in; (void)out_size; (void)ws_size;

    const float* x    = (const float*)d_in[0];
    const int*   ei   = (const int*)d_in[1];
    const float* Wres = (const float*)d_in[3];
    const float* bres = (const float*)d_in[4];
    const float* Wk   = (const float*)d_in[5];
    const float* bk   = (const float*)d_in[6];
    const float* Wq   = (const float*)d_in[7];
    const float* bq   = (const float*)d_in[8];
    const float* Wv   = (const float*)d_in[9];
    const float* bv   = (const float*)d_in[10];
    const float* Wsk  = (const float*)d_in[11];
    const float* bsk  = (const float*)d_in[12];
    const float* g1l  = (const float*)d_in[13];
    const float* b1l  = (const float*)d_in[14];
    const float* g1a  = (const float*)d_in[15];
    const float* b1a  = (const float*)d_in[16];
    const float* Win  = (const float*)d_in[17];
    const float* bin  = (const float*)d_in[18];
    const float* Wout = (const float*)d_in[19];
    const float* bout = (const float*)d_in[20];
    const float* W1   = (const float*)d_in[21];
    const float* b1   = (const float*)d_in[22];
    const float* W2   = (const float*)d_in[23];
    const float* b2   = (const float*)d_in[24];
    const float* g2   = (const float*)d_in[25];
    const float* b2g  = (const float*)d_in[26];
    float* out = (float*)d_out;

    float* ws     = (float*)d_ws;
    float* hin1   = ws;                 // [N,128]
    float* kbuf   = ws + NM;            // [N,128]   (later: attnqkv / hattn / ff1)
    float* qbuf   = ws + 2 * NM;        // [N,128]
    float* vbuf   = ws + 3 * NM;        // [N,128]
    float* agg    = ws + 4 * NM;        // [N,128]   (later: ctx / ff2)
    float* hlocal = ws + 5 * NM;        // [N,128]
    float* hbuf   = ws + 6 * NM;        // [N,128]
    float* attnqkv = kbuf;              // [N,384] over kbuf|qbuf|vbuf (dead then)
    float* ctx    = agg;                // [N,128] (agg dead after bn_local)
    float* hattn  = kbuf;               // [N,128] (attnqkv dead after attn)
    float* ff1    = ws + 2 * NM;        // [N,256]
    float* ff2    = agg;                // [N,128] (ctx dead after out_proj)

    dim3 blk(256);

    // --- node-wise projections ---
    sgemm_kernel<1><<<dim3(2, 512), blk, 0, stream>>>(x, Wres, bres, hin1, 128, 128);
    sgemm_kernel<0><<<dim3(2, 512), blk, 0, stream>>>(x, Wk,   bk,   kbuf, 128, 128);
    sgemm_kernel<0><<<dim3(2, 512), blk, 0, stream>>>(x, Wq,   bq,   qbuf, 128, 128);
    sgemm_kernel<0><<<dim3(2, 512), blk, 0, stream>>>(x, Wv,   bv,   vbuf, 128, 128);
    sgemm_kernel<0><<<dim3(2, 512), blk, 0, stream>>>(x, Wsk,  bsk,  agg,  128, 128);

    // --- local path: gated message passing (agg pre-holds skip) ---
    edge_kernel<<<dim3((N_EDGES * 32) / 256), blk, 0, stream>>>(kbuf, qbuf, vbuf, ei, agg);
    bn_add_kernel<<<dim3(NM / 4 / 256), blk, 0, stream>>>(hin1, agg, g1l, b1l, hlocal);

    // --- global path: dense MHA ---
    sgemm_kernel<0><<<dim3(6, 512), blk, 0, stream>>>(hin1, Win, bin, attnqkv, 128, 384);
    attn_kernel<<<dim3(512), blk, 0, stream>>>(attnqkv, ctx);
    sgemm_kernel<0><<<dim3(2, 512), blk, 0, stream>>>(ctx, Wout, bout, hattn, 128, 128);

    // --- combine: h = hlocal + bn(hin1 + hattn) ---
    combine_kernel<<<dim3(NM / 4 / 256), blk, 0, stream>>>(hlocal, hin1, hattn, g1a, b1a, hbuf);

    // --- FFN ---
    sgemm_kernel<1><<<dim3(4, 512), blk, 0, stream>>>(hbuf, W1, b1, ff1, 128, 256);
    sgemm_kernel<0><<<dim3(2, 512), blk, 0, stream>>>(ff1, W2, b2, ff2, 256, 128);

    // --- final BN ---
    bn_add_kernel<<<dim3(NM / 4 / 256), blk, 0, stream>>>(hbuf, ff2, g2, b2g, out);
}

// Round 2
// 624.097 us; speedup vs baseline: 2.1941x; 2.1941x over previous
//
#include <hip/hip_runtime.h>
#include <math.h>

#define N_NODES 32768
#define N_EDGES 524288
#define DIM     128

static constexpr size_t NM = (size_t)N_NODES * DIM;   // 4194304 floats

// ---------------------------------------------------------------------------
// Tiled SGEMM: C[M,Nout] = act(A[M,K] * W[Nout,K]^T + bias)
// 64x64 tile per block, 256 threads, 4x4 per thread, K-tile 16.
// ACT: 0 = none, 1 = relu
// ---------------------------------------------------------------------------
template<int ACT>
__global__ __launch_bounds__(256)
void sgemm_kernel(const float* __restrict__ A, const float* __restrict__ W,
                  const float* __restrict__ bias, float* __restrict__ C,
                  int K, int Nout)
{
    __shared__ float As[16][68];
    __shared__ float Bs[16][68];

    const int tx = threadIdx.x & 15;
    const int ty = threadIdx.x >> 4;
    const int bm = blockIdx.y * 64;
    const int bn = blockIdx.x * 64;

    float acc[4][4] = {};

    for (int k0 = 0; k0 < K; k0 += 16) {
        __syncthreads();
        #pragma unroll
        for (int i = 0; i < 4; ++i) {
            int idx = threadIdx.x + i * 256;
            int kk  = idx & 15;
            int m   = idx >> 4;
            As[kk][m] = A[(size_t)(bm + m) * K + k0 + kk];
            Bs[kk][m] = W[(size_t)(bn + m) * K + k0 + kk];
        }
        __syncthreads();
        #pragma unroll
        for (int kk = 0; kk < 16; ++kk) {
            float4 a4 = *(const float4*)&As[kk][ty * 4];
            float4 b4 = *(const float4*)&Bs[kk][tx * 4];
            float av[4] = {a4.x, a4.y, a4.z, a4.w};
            float bv[4] = {b4.x, b4.y, b4.z, b4.w};
            #pragma unroll
            for (int r = 0; r < 4; ++r)
                #pragma unroll
                for (int c = 0; c < 4; ++c)
                    acc[r][c] += av[r] * bv[c];
        }
    }

    #pragma unroll
    for (int r = 0; r < 4; ++r) {
        int row = bm + ty * 4 + r;
        int col = bn + tx * 4;
        float4 o;
        float* po = (float*)&o;
        #pragma unroll
        for (int c = 0; c < 4; ++c) {
            float v = acc[r][c] + bias[col + c];
            if (ACT == 1) v = fmaxf(v, 0.0f);
            po[c] = v;
        }
        *(float4*)&C[(size_t)row * Nout + col] = o;
    }
}

// ---------------------------------------------------------------------------
// CSR build: histogram -> scan -> scatter (dst-sorted src list)
// ---------------------------------------------------------------------------
__global__ __launch_bounds__(256)
void hist_kernel(const int* __restrict__ ei, int* __restrict__ deg)
{
    int e = blockIdx.x * 256 + threadIdx.x;
    atomicAdd(&deg[ei[N_EDGES + e]], 1);
}

__global__ __launch_bounds__(1024)
void scan_kernel(const int* __restrict__ deg, int* __restrict__ offsets,
                 int* __restrict__ cursor)
{
    __shared__ int bufA[1024];
    __shared__ int bufB[1024];
    const int t = threadIdx.x;
    const int base = t * 32;

    int local[32];
    int run = 0;
    #pragma unroll
    for (int j = 0; j < 32; ++j) { local[j] = run; run += deg[base + j]; }

    int* src = bufA;
    int* dst = bufB;
    src[t] = run;
    __syncthreads();
    for (int off = 1; off < 1024; off <<= 1) {
        int v = src[t] + ((t >= off) ? src[t - off] : 0);
        dst[t] = v;
        __syncthreads();
        int* tmp = src; src = dst; dst = tmp;
    }
    int blockbase = (t == 0) ? 0 : src[t - 1];

    #pragma unroll
    for (int j = 0; j < 32; ++j) {
        int v = blockbase + local[j];
        offsets[base + j] = v;
        cursor[base + j]  = v;
    }
    if (t == 1023) offsets[N_NODES] = src[1023];
}

__global__ __launch_bounds__(256)
void scatter_kernel(const int* __restrict__ ei, int* __restrict__ cursor,
                    int* __restrict__ csr_src)
{
    int e = blockIdx.x * 256 + threadIdx.x;
    int d = ei[N_EDGES + e];
    int pos = atomicAdd(&cursor[d], 1);
    csr_src[pos] = ei[e];
}

// ---------------------------------------------------------------------------
// Gather aggregation + skip + BN fused:
//   hlocal[d] = (hin1[d] + skip[d] + sum_e sigmoid(k[d]+q[s])*v[s]) * g*rs + b
// One wave per node; lane owns 2 columns (float2) -> 512B coalesced row reads.
// No atomics.
// ---------------------------------------------------------------------------
__global__ __launch_bounds__(256)
void gather_local_kernel(const float* __restrict__ kf, const float* __restrict__ qf,
                         const float* __restrict__ vf, const float* __restrict__ skip,
                         const float* __restrict__ hin1,
                         const int* __restrict__ offsets, const int* __restrict__ csr_src,
                         const float* __restrict__ g, const float* __restrict__ beta,
                         float* __restrict__ hlocal)
{
    const int d    = blockIdx.x * 4 + (threadIdx.x >> 6);
    const int lane = threadIdx.x & 63;
    const int c    = lane * 2;
    const float rs = 0.9999950000374998f;     // 1/sqrt(1+1e-5)

    float2 k2 = *(const float2*)(kf + (size_t)d * DIM + c);
    const int beg = offsets[d];
    const int end = offsets[d + 1];

    float ax = 0.0f, ay = 0.0f;
    for (int i = beg; i < end; ++i) {
        int s = csr_src[i];
        float2 q2 = *(const float2*)(qf + (size_t)s * DIM + c);
        float2 v2 = *(const float2*)(vf + (size_t)s * DIM + c);
        ax += v2.x / (1.0f + __expf(-(k2.x + q2.x)));
        ay += v2.y / (1.0f + __expf(-(k2.y + q2.y)));
    }

    float2 sk = *(const float2*)(skip + (size_t)d * DIM + c);
    float2 hi = *(const float2*)(hin1 + (size_t)d * DIM + c);
    float2 gv = *(const float2*)(g + c);
    float2 bt = *(const float2*)(beta + c);
    float2 o;
    o.x = (hi.x + sk.x + ax) * (gv.x * rs) + bt.x;
    o.y = (hi.y + sk.y + ay) * (gv.y * rs) + bt.y;
    *(float2*)(hlocal + (size_t)d * DIM + c) = o;
}

// ---------------------------------------------------------------------------
// Flash attention over equal-size graphs. One thread = one query row.
// ---------------------------------------------------------------------------
__global__ __launch_bounds__(256)
void attn_kernel(const float* __restrict__ qkv, float* __restrict__ ctx)
{
    const int blk = blockIdx.x;          // B*H*2 = 512 blocks
    const int qt  = blk & 1;
    const int h   = (blk >> 1) & 3;
    const int b   = blk >> 3;

    const int qrow = qt * 256 + threadIdx.x;
    const int node = b * 512 + qrow;
    const float scale = 0.17677669529663687f;   // 1/sqrt(32)

    float qreg[32];
    {
        const float* qp = qkv + (size_t)node * 384 + h * 32;
        #pragma unroll
        for (int dd = 0; dd < 8; ++dd) {
            float4 q4 = *(const float4*)(qp + dd * 4);
            qreg[dd*4+0] = q4.x * scale; qreg[dd*4+1] = q4.y * scale;
            qreg[dd*4+2] = q4.z * scale; qreg[dd*4+3] = q4.w * scale;
        }
    }

    float m = -1e30f, l = 0.0f;
    float acc[32] = {};

    __shared__ float Ks[128][32];
    __shared__ float Vs[128][32];

    for (int kc = 0; kc < 4; ++kc) {
        __syncthreads();
        #pragma unroll
        for (int i = 0; i < 4; ++i) {
            int idx = threadIdx.x + i * 256;      // 0..1023
            int row = idx >> 3;
            int cc  = (idx & 7) * 4;
            int knode = b * 512 + kc * 128 + row;
            const float* base = qkv + (size_t)knode * 384 + h * 32;
            *(float4*)&Ks[row][cc] = *(const float4*)(base + 128 + cc);
            *(float4*)&Vs[row][cc] = *(const float4*)(base + 256 + cc);
        }
        __syncthreads();

        for (int j = 0; j < 128; ++j) {
            float sc = 0.0f;
            #pragma unroll
            for (int dd = 0; dd < 8; ++dd) {
                float4 k4 = *(const float4*)&Ks[j][dd * 4];
                sc += qreg[dd*4+0]*k4.x + qreg[dd*4+1]*k4.y
                    + qreg[dd*4+2]*k4.z + qreg[dd*4+3]*k4.w;
            }
            if (sc > m) {
                float corr = __expf(m - sc);
                l *= corr;
                #pragma unroll
                for (int dd = 0; dd < 32; ++dd) acc[dd] *= corr;
                m = sc;
            }
            float p = __expf(sc - m);
            l += p;
            #pragma unroll
            for (int dd = 0; dd < 8; ++dd) {
                float4 v4 = *(const float4*)&Vs[j][dd * 4];
                acc[dd*4+0] += p * v4.x; acc[dd*4+1] += p * v4.y;
                acc[dd*4+2] += p * v4.z; acc[dd*4+3] += p * v4.w;
            }
        }
    }

    float inv = 1.0f / l;
    float* op = ctx + (size_t)node * DIM + h * 32;
    #pragma unroll
    for (int dd = 0; dd < 8; ++dd) {
        float4 o;
        o.x = acc[dd*4+0]*inv; o.y = acc[dd*4+1]*inv;
        o.z = acc[dd*4+2]*inv; o.w = acc[dd*4+3]*inv;
        *(float4*)(op + dd * 4) = o;
    }
}

// ---------------------------------------------------------------------------
// Elementwise: out = (a + b) * (g[c]/sqrt(1+eps)) + beta[c]
// ---------------------------------------------------------------------------
__global__ __launch_bounds__(256)
void bn_add_kernel(const float* __restrict__ a, const float* __restrict__ b,
                   const float* __restrict__ g, const float* __restrict__ beta,
                   float* __restrict__ out)
{
    int t = blockIdx.x * 256 + threadIdx.x;
    int c = (t & 31) * 4;
    const float rs = 0.9999950000374998f;
    float4 av = *(const float4*)(a + (size_t)t * 4);
    float4 bv = *(const float4*)(b + (size_t)t * 4);
    float4 gv = *(const float4*)(g + c);
    float4 bt = *(const float4*)(beta + c);
    float4 o;
    o.x = (av.x + bv.x) * (gv.x * rs) + bt.x;
    o.y = (av.y + bv.y) * (gv.y * rs) + bt.y;
    o.z = (av.z + bv.z) * (gv.z * rs) + bt.z;
    o.w = (av.w + bv.w) * (gv.w * rs) + bt.w;
    *(float4*)(out + (size_t)t * 4) = o;
}

// h = hlocal + bn(hin1 + hattn)
__global__ __launch_bounds__(256)
void combine_kernel(const float* __restrict__ hlocal, const float* __restrict__ hin1,
                    const float* __restrict__ hattn, const float* __restrict__ g,
                    const float* __restrict__ beta, float* __restrict__ out)
{
    int t = blockIdx.x * 256 + threadIdx.x;
    int c = (t & 31) * 4;
    const float rs = 0.9999950000374998f;
    float4 hl = *(const float4*)(hlocal + (size_t)t * 4);
    float4 hi = *(const float4*)(hin1   + (size_t)t * 4);
    float4 ha = *(const float4*)(hattn  + (size_t)t * 4);
    float4 gv = *(const float4*)(g + c);
    float4 bt = *(const float4*)(beta + c);
    float4 o;
    o.x = hl.x + (hi.x + ha.x) * (gv.x * rs) + bt.x;
    o.y = hl.y + (hi.y + ha.y) * (gv.y * rs) + bt.y;
    o.z = hl.z + (hi.z + ha.z) * (gv.z * rs) + bt.z;
    o.w = hl.w + (hi.w + ha.w) * (gv.w * rs) + bt.w;
    *(float4*)(out + (size_t)t * 4) = o;
}

// ---------------------------------------------------------------------------
extern "C" void kernel_launch(void* const* d_in, const int* in_sizes, int n_in,
                              void* d_out, int out_size, void* d_ws, size_t ws_size,
                              hipStream_t stream)
{
    (void)in_sizes; (void)n_in; (void)out_size; (void)ws_size;

    const float* x    = (const float*)d_in[0];
    const int*   ei   = (const int*)d_in[1];
    const float* Wres = (const float*)d_in[3];
    const float* bres = (const float*)d_in[4];
    const float* Wk   = (const float*)d_in[5];
    const float* bk   = (const float*)d_in[6];
    const float* Wq   = (const float*)d_in[7];
    const float* bq   = (const float*)d_in[8];
    const float* Wv   = (const float*)d_in[9];
    const float* bv   = (const float*)d_in[10];
    const float* Wsk  = (const float*)d_in[11];
    const float* bsk  = (const float*)d_in[12];
    const float* g1l  = (const float*)d_in[13];
    const float* b1l  = (const float*)d_in[14];
    const float* g1a  = (const float*)d_in[15];
    const float* b1a  = (const float*)d_in[16];
    const float* Win  = (const float*)d_in[17];
    const float* bin  = (const float*)d_in[18];
    const float* Wout = (const float*)d_in[19];
    const float* bout = (const float*)d_in[20];
    const float* W1   = (const float*)d_in[21];
    const float* b1   = (const float*)d_in[22];
    const float* W2   = (const float*)d_in[23];
    const float* b2   = (const float*)d_in[24];
    const float* g2   = (const float*)d_in[25];
    const float* b2g  = (const float*)d_in[26];
    float* out = (float*)d_out;

    float* ws     = (float*)d_ws;
    float* hin1   = ws;                 // [N,128]
    float* kbuf   = ws + NM;            // [N,128]
    float* qbuf   = ws + 2 * NM;        // [N,128]
    float* vbuf   = ws + 3 * NM;        // [N,128]
    float* skip   = ws + 4 * NM;        // [N,128]   (later: ctx / ff2)
    float* hlocal = ws + 5 * NM;        // [N,128]
    float* hbuf   = ws + 6 * NM;        // [N,128]   (CSR ints live here first)
    float* attnqkv = kbuf;              // [N,384] over kbuf|qbuf|vbuf
    float* ctx    = skip;               // [N,128] (skip dead after gather)
    float* hattn  = kbuf;               // [N,128]
    float* ff1    = ws + 2 * NM;        // [N,256]
    float* ff2    = skip;               // [N,128]

    // CSR scratch overlaid on hbuf region (dead until combine_kernel)
    int* deg     = (int*)(ws + 6 * NM);           // [N]
    int* offsets = deg + N_NODES;                 // [N+1]
    int* cursor  = offsets + N_NODES + 1;         // [N]
    int* csr_src = cursor + N_NODES;              // [E]

    dim3 blk(256);

    // --- node-wise projections ---
    sgemm_kernel<1><<<dim3(2, 512), blk, 0, stream>>>(x, Wres, bres, hin1, 128, 128);
    sgemm_kernel<0><<<dim3(2, 512), blk, 0, stream>>>(x, Wk,   bk,   kbuf, 128, 128);
    sgemm_kernel<0><<<dim3(2, 512), blk, 0, stream>>>(x, Wq,   bq,   qbuf, 128, 128);
    sgemm_kernel<0><<<dim3(2, 512), blk, 0, stream>>>(x, Wv,   bv,   vbuf, 128, 128);
    sgemm_kernel<0><<<dim3(2, 512), blk, 0, stream>>>(x, Wsk,  bsk,  skip, 128, 128);

    // --- CSR build (no host sync; all on stream) ---
    hipMemsetAsync((void*)deg, 0, N_NODES * sizeof(int), stream);
    hist_kernel<<<dim3(N_EDGES / 256), blk, 0, stream>>>(ei, deg);
    scan_kernel<<<dim3(1), dim3(1024), 0, stream>>>(deg, offsets, cursor);
    scatter_kernel<<<dim3(N_EDGES / 256), blk, 0, stream>>>(ei, cursor, csr_src);

    // --- local path: gather aggregation, fused skip-add + BN ---
    gather_local_kernel<<<dim3(N_NODES / 4), blk, 0, stream>>>(
        kbuf, qbuf, vbuf, skip, hin1, offsets, csr_src, g1l, b1l, hlocal);

    // --- global path: dense MHA ---
    sgemm_kernel<0><<<dim3(6, 512), blk, 0, stream>>>(hin1, Win, bin, attnqkv, 128, 384);
    attn_kernel<<<dim3(512), blk, 0, stream>>>(attnqkv, ctx);
    sgemm_kernel<0><<<dim3(2, 512), blk, 0, stream>>>(ctx, Wout, bout, hattn, 128, 128);

    // --- combine: h = hlocal + bn(hin1 + hattn) ---
    combine_kernel<<<dim3(NM / 4 / 256), blk, 0, stream>>>(hlocal, hin1, hattn, g1a, b1a, hbuf);

    // --- FFN ---
    sgemm_kernel<1><<<dim3(4, 512), blk, 0, stream>>>(hbuf, W1, b1, ff1, 128, 256);
    sgemm_kernel<0><<<dim3(2, 512), blk, 0, stream>>>(ff1, W2, b2, ff2, 256, 128);

    // --- final BN ---
    bn_add_kernel<<<dim3(NM / 4 / 256), blk, 0, stream>>>(hbuf, ff2, g2, b2g, out);
}

// Round 3
// 301.246 us; speedup vs baseline: 4.5456x; 2.0717x over previous
//
#include <hip/hip_runtime.h>
#include <math.h>

#define N_NODES 32768
#define N_EDGES 524288
#define DIM     128

static constexpr size_t NM = (size_t)N_NODES * DIM;   // 4194304 floats

typedef __attribute__((ext_vector_type(8)))  short bf8;     // 8 bf16
typedef __attribute__((ext_vector_type(4)))  float f32x4;
typedef __attribute__((ext_vector_type(16))) float f32x16;

// float -> bf16 (RNE) bit trick
__device__ __forceinline__ short f2bs(float x) {
    union { float f; unsigned int u; } v; v.f = x;
    unsigned int r = v.u + 0x7fffu + ((v.u >> 16) & 1u);
    return (short)(r >> 16);
}
__device__ __forceinline__ unsigned int pk2(float a, float b) {
    return (unsigned int)(unsigned short)f2bs(a) |
           ((unsigned int)(unsigned short)f2bs(b) << 16);
}
__device__ __forceinline__ float2 bs2f(unsigned int u) {
    union { unsigned int a; float f; } lo, hi;
    lo.a = u << 16; hi.a = u & 0xffff0000u;
    float2 r; r.x = lo.f; r.y = hi.f; return r;
}

// ---------------------------------------------------------------------------
// cvt: x (f32->bf16) and all 9 weight matrices (f32->bf16) into wbf
// wbf offsets (elements): Wres 0, Wk 16384, Wq 32768, Wv 49152, Wskip 65536,
//                         Win 81920, Wout 131072, W1 147456, W2 180224 (end 212992)
// ---------------------------------------------------------------------------
__global__ __launch_bounds__(256)
void cvt_kernel(const float* __restrict__ x,
                const float* __restrict__ w0, const float* __restrict__ w1,
                const float* __restrict__ w2, const float* __restrict__ w3,
                const float* __restrict__ w4, const float* __restrict__ w5,
                const float* __restrict__ w6, const float* __restrict__ w7,
                const float* __restrict__ w8,
                short* __restrict__ xb, short* __restrict__ wbf)
{
    long long t = (long long)blockIdx.x * 256 + threadIdx.x;
    long long i4 = t * 4;
    if (i4 < (long long)NM) {
        float4 v = *(const float4*)(x + i4);
        short4 o; o.x = f2bs(v.x); o.y = f2bs(v.y); o.z = f2bs(v.z); o.w = f2bs(v.w);
        *(short4*)(xb + i4) = o;
    } else {
        int j = (int)(i4 - (long long)NM);
        if (j >= 212992) return;
        const float* src; int off;
        if      (j <  16384) { src = w0; off = 0; }
        else if (j <  32768) { src = w1; off = 16384; }
        else if (j <  49152) { src = w2; off = 32768; }
        else if (j <  65536) { src = w3; off = 49152; }
        else if (j <  81920) { src = w4; off = 65536; }
        else if (j < 131072) { src = w5; off = 81920; }
        else if (j < 147456) { src = w6; off = 131072; }
        else if (j < 180224) { src = w7; off = 147456; }
        else                 { src = w8; off = 180224; }
        float4 v = *(const float4*)(src + (j - off));
        short4 o; o.x = f2bs(v.x); o.y = f2bs(v.y); o.z = f2bs(v.z); o.w = f2bs(v.w);
        *(short4*)(wbf + j) = o;
    }
}

// ---------------------------------------------------------------------------
// bf16 MFMA GEMM: C[M,Nout] = act((A[M,K] @ W[Nout,K]^T + bias) * scale?)
// 128x128 block tile, 4 waves (2x2), each wave 64x64 via 4x4 frags of 16x16x32.
// OUT: 0=f32, 1=bf16, 2=dual. A,W are bf16 row-major (K contiguous).
// ---------------------------------------------------------------------------
template<int ACT, int OUT>
__global__ __launch_bounds__(256)
void mgemm(const short* __restrict__ A, const short* __restrict__ Wb,
           const float* __restrict__ bias, float* __restrict__ Cf,
           short* __restrict__ Cb, int K, int Nout, int scale_cols, float qscale)
{
    const int lane = threadIdx.x & 63;
    const int wid  = threadIdx.x >> 6;
    const int m0 = blockIdx.y * 128 + (wid >> 1) * 64;
    const int n0 = blockIdx.x * 128 + (wid & 1) * 64;
    const int lrow = lane & 15;
    const int lk   = (lane >> 4) * 8;

    f32x4 acc[4][4] = {};

    const short* Ap = A  + (size_t)(m0 + lrow) * K + lk;
    const short* Wp = Wb + (size_t)(n0 + lrow) * K + lk;

    for (int ks = 0; ks < K; ks += 32) {
        bf8 af[4], wf[4];
        #pragma unroll
        for (int i = 0; i < 4; ++i) {
            af[i] = *(const bf8*)(Ap + (size_t)i * 16 * K + ks);
            wf[i] = *(const bf8*)(Wp + (size_t)i * 16 * K + ks);
        }
        #pragma unroll
        for (int i = 0; i < 4; ++i)
            #pragma unroll
            for (int j = 0; j < 4; ++j)
                acc[i][j] = __builtin_amdgcn_mfma_f32_16x16x32_bf16(
                                af[i], wf[j], acc[i][j], 0, 0, 0);
    }

    const int rbase = (lane >> 4) * 4;
    #pragma unroll
    for (int j = 0; j < 4; ++j) {
        int col = n0 + j * 16 + lrow;
        float bcol = bias[col];
        float sc = (col < scale_cols) ? qscale : 1.0f;
        #pragma unroll
        for (int i = 0; i < 4; ++i) {
            #pragma unroll
            for (int r = 0; r < 4; ++r) {
                int row = m0 + i * 16 + rbase + r;
                float v = (acc[i][j][r] + bcol) * sc;
                if (ACT == 1) v = fmaxf(v, 0.0f);
                if (OUT == 0 || OUT == 2) Cf[(size_t)row * Nout + col] = v;
                if (OUT == 1 || OUT == 2) Cb[(size_t)row * Nout + col] = f2bs(v);
            }
        }
    }
}

// ---------------------------------------------------------------------------
// CSR build: histogram -> scan -> scatter (dst-sorted src list)
// ---------------------------------------------------------------------------
__global__ __launch_bounds__(256)
void hist_kernel(const int* __restrict__ ei, int* __restrict__ deg)
{
    int e = blockIdx.x * 256 + threadIdx.x;
    atomicAdd(&deg[ei[N_EDGES + e]], 1);
}

__global__ __launch_bounds__(1024)
void scan_kernel(const int* __restrict__ deg, int* __restrict__ offsets,
                 int* __restrict__ cursor)
{
    __shared__ int bufA[1024];
    __shared__ int bufB[1024];
    const int t = threadIdx.x;
    const int base = t * 32;

    int local[32];
    int run = 0;
    #pragma unroll
    for (int j = 0; j < 32; ++j) { local[j] = run; run += deg[base + j]; }

    int* src = bufA;
    int* dst = bufB;
    src[t] = run;
    __syncthreads();
    for (int off = 1; off < 1024; off <<= 1) {
        int v = src[t] + ((t >= off) ? src[t - off] : 0);
        dst[t] = v;
        __syncthreads();
        int* tmp = src; src = dst; dst = tmp;
    }
    int blockbase = (t == 0) ? 0 : src[t - 1];

    #pragma unroll
    for (int j = 0; j < 32; ++j) {
        int v = blockbase + local[j];
        offsets[base + j] = v;
        cursor[base + j]  = v;
    }
    if (t == 1023) offsets[N_NODES] = src[1023];
}

__global__ __launch_bounds__(256)
void scatter_kernel(const int* __restrict__ ei, int* __restrict__ cursor,
                    int* __restrict__ csr_src)
{
    int e = blockIdx.x * 256 + threadIdx.x;
    int d = ei[N_EDGES + e];
    int pos = atomicAdd(&cursor[d], 1);
    csr_src[pos] = ei[e];
}

// ---------------------------------------------------------------------------
// Gather aggregation (bf16 inputs) + skip + BN fused. One wave per node.
// ---------------------------------------------------------------------------
__global__ __launch_bounds__(256)
void gather_local_kernel(const unsigned int* __restrict__ kb,
                         const unsigned int* __restrict__ qb,
                         const unsigned int* __restrict__ vb,
                         const unsigned int* __restrict__ skipb,
                         const float* __restrict__ hin1,
                         const int* __restrict__ offsets, const int* __restrict__ csr_src,
                         const float* __restrict__ g, const float* __restrict__ beta,
                         float* __restrict__ hlocal)
{
    const int d    = blockIdx.x * 4 + (threadIdx.x >> 6);
    const int lane = threadIdx.x & 63;          // owns cols 2*lane, 2*lane+1
    const float rs = 0.9999950000374998f;       // 1/sqrt(1+1e-5)

    float2 k2 = bs2f(kb[(size_t)d * 64 + lane]);
    const int beg = offsets[d];
    const int end = offsets[d + 1];

    float ax = 0.0f, ay = 0.0f;
    for (int i = beg; i < end; ++i) {
        int s = csr_src[i];
        float2 q2 = bs2f(qb[(size_t)s * 64 + lane]);
        float2 v2 = bs2f(vb[(size_t)s * 64 + lane]);
        ax += v2.x / (1.0f + __expf(-(k2.x + q2.x)));
        ay += v2.y / (1.0f + __expf(-(k2.y + q2.y)));
    }

    float2 sk = bs2f(skipb[(size_t)d * 64 + lane]);
    float2 hi = *(const float2*)(hin1 + (size_t)d * DIM + lane * 2);
    float2 gv = *(const float2*)(g + lane * 2);
    float2 bt = *(const float2*)(beta + lane * 2);
    float2 o;
    o.x = (hi.x + sk.x + ax) * (gv.x * rs) + bt.x;
    o.y = (hi.y + sk.y + ay) * (gv.y * rs) + bt.y;
    *(float2*)(hlocal + (size_t)d * DIM + lane * 2) = o;
}

// ---------------------------------------------------------------------------
// MFMA flash attention. One block (256 thr, 4 waves) per (b,h); 256 blocks.
// Swapped QK^T: S^T[key][q] = K·Q^T via mfma_32x32x16; softmax per q-col;
// PV as O^T = V^T · P with V transposed+swizzled in LDS.
// qkv: [N,384] bf16 (q pre-scaled by 1/sqrt(32)); ctx: [N,128] bf16.
// ---------------------------------------------------------------------------
__device__ __forceinline__ void lswap(unsigned int& X, unsigned int& Y, bool hi) {
    unsigned int Xs = (unsigned int)__shfl_xor((int)X, 32);
    unsigned int Ys = (unsigned int)__shfl_xor((int)Y, 32);
    unsigned int Xn = hi ? Ys : X;
    unsigned int Yn = hi ? Y  : Xs;
    X = Xn; Y = Yn;
}

__global__ __launch_bounds__(256)
void attn_mfma(const short* __restrict__ qkv, short* __restrict__ ctx)
{
    __shared__ __align__(16) short ldsK[512 * 32];    // 32 KB, reused as O-stage
    __shared__ __align__(16) short ldsVt[32 * 512];   // 32 KB, swizzled

    const int b = blockIdx.x >> 2;
    const int h = blockIdx.x & 3;
    const int tid  = threadIdx.x;
    const int lane = tid & 63;
    const int wid  = tid >> 6;
    const int lq = lane & 31;
    const int lg = lane >> 5;
    const size_t gbase = (size_t)(b * 512) * 384 + h * 32;

    // --- stage K rows: ldsK[key][0..31] ---
    #pragma unroll
    for (int i = 0; i < 8; ++i) {
        int c = tid + i * 256;              // 0..2047
        int key = c >> 2, part = c & 3;
        bf8 v = *(const bf8*)(qkv + gbase + (size_t)key * 384 + 128 + part * 8);
        *(bf8*)(ldsK + key * 32 + part * 8) = v;
    }
    // --- stage V transposed: ldsVt row d, byte (key*2) ^ ((d&7)<<4) ---
    {
        int p = tid;                        // key pair (2p, 2p+1)
        const short* v0 = qkv + gbase + (size_t)(2 * p) * 384 + 256;
        const short* v1 = v0 + 384;
        bf8 r0[4], r1[4];
        #pragma unroll
        for (int i = 0; i < 4; ++i) { r0[i] = *(const bf8*)(v0 + i * 8);
                                      r1[i] = *(const bf8*)(v1 + i * 8); }
        #pragma unroll
        for (int d = 0; d < 32; ++d) {
            unsigned int w = ((unsigned int)(unsigned short)r0[d >> 3][d & 7]) |
                             (((unsigned int)(unsigned short)r1[d >> 3][d & 7]) << 16);
            *(unsigned int*)((char*)ldsVt + d * 1024 + ((4 * p) ^ ((d & 7) << 4))) = w;
        }
    }
    // --- Q fragments in registers (q pre-scaled at in_proj) ---
    const int qw = wid * 128;
    bf8 qf[4][2];
    #pragma unroll
    for (int qg = 0; qg < 4; ++qg)
        #pragma unroll
        for (int kh = 0; kh < 2; ++kh)
            qf[qg][kh] = *(const bf8*)(qkv + gbase +
                           (size_t)(qw + qg * 32 + lq) * 384 + kh * 16 + lg * 8);
    __syncthreads();

    const f32x16 Z16 = {0.f,0.f,0.f,0.f,0.f,0.f,0.f,0.f,0.f,0.f,0.f,0.f,0.f,0.f,0.f,0.f};
    f32x16 o[4] = {Z16, Z16, Z16, Z16};
    float mreg[4] = {-1e30f, -1e30f, -1e30f, -1e30f};
    float lreg[4] = {0.f, 0.f, 0.f, 0.f};
    const bool hi = (lg != 0);

    for (int kt = 0; kt < 16; ++kt) {
        bf8 ak[2], vt[2];
        #pragma unroll
        for (int kh = 0; kh < 2; ++kh) {
            ak[kh] = *(const bf8*)(ldsK + (kt * 32 + lq) * 32 + kh * 16 + lg * 8);
            int kbyte = (kt * 32 + kh * 16 + lg * 8) * 2;
            vt[kh] = *(const bf8*)((const char*)ldsVt + lq * 1024 +
                                   (kbyte ^ ((lq & 7) << 4)));
        }
        #pragma unroll
        for (int qg = 0; qg < 4; ++qg) {
            f32x16 s = Z16;
            s = __builtin_amdgcn_mfma_f32_32x32x16_bf16(ak[0], qf[qg][0], s, 0, 0, 0);
            s = __builtin_amdgcn_mfma_f32_32x32x16_bf16(ak[1], qf[qg][1], s, 0, 0, 0);
            // softmax over the 16 key-rows held in regs (+ partner half-wave)
            float mt = s[0];
            #pragma unroll
            for (int r = 1; r < 16; ++r) mt = fmaxf(mt, s[r]);
            mt = fmaxf(mt, __shfl_xor(mt, 32));
            float mnew = fmaxf(mreg[qg], mt);
            float corr = __expf(mreg[qg] - mnew);
            mreg[qg] = mnew;
            float p[16]; float ps = 0.f;
            #pragma unroll
            for (int r = 0; r < 16; ++r) { p[r] = __expf(s[r] - mnew); ps += p[r]; }
            ps += __shfl_xor(ps, 32);
            lreg[qg] = lreg[qg] * corr + ps;
            #pragma unroll
            for (int r = 0; r < 16; ++r) o[qg][r] *= corr;
            // pack P and redistribute to B-operand layout
            unsigned int w0 = pk2(p[0],  p[1]),  w1 = pk2(p[2],  p[3]);
            unsigned int w2 = pk2(p[4],  p[5]),  w3 = pk2(p[6],  p[7]);
            unsigned int w4 = pk2(p[8],  p[9]),  w5 = pk2(p[10], p[11]);
            unsigned int w6 = pk2(p[12], p[13]), w7 = pk2(p[14], p[15]);
            lswap(w0, w2, hi); lswap(w1, w3, hi);
            lswap(w4, w6, hi); lswap(w5, w7, hi);
            union { unsigned int u[4]; bf8 v; } P0, P1;
            P0.u[0] = w0; P0.u[1] = w1; P0.u[2] = w2; P0.u[3] = w3;
            P1.u[0] = w4; P1.u[1] = w5; P1.u[2] = w6; P1.u[3] = w7;
            o[qg] = __builtin_amdgcn_mfma_f32_32x32x16_bf16(vt[0], P0.v, o[qg], 0, 0, 0);
            o[qg] = __builtin_amdgcn_mfma_f32_32x32x16_bf16(vt[1], P1.v, o[qg], 0, 0, 0);
        }
    }

    // --- epilogue: O^T regs -> LDS (swizzled) -> coalesced global bf16 ---
    __syncthreads();                       // all waves done reading ldsK
    short* ldsO = ldsK;                    // [512 q][32 d], byte ^ ((q&7)<<3)
    #pragma unroll
    for (int qg = 0; qg < 4; ++qg) {
        float inv = 1.0f / lreg[qg];
        int q = qw + qg * 32 + lq;
        #pragma unroll
        for (int b4 = 0; b4 < 4; ++b4) {   // regs 4*b4..+3 -> d = 8*b4 + 4*lg ..+3
            short4 pkv;
            pkv.x = f2bs(o[qg][b4 * 4 + 0] * inv);
            pkv.y = f2bs(o[qg][b4 * 4 + 1] * inv);
            pkv.z = f2bs(o[qg][b4 * 4 + 2] * inv);
            pkv.w = f2bs(o[qg][b4 * 4 + 3] * inv);
            int dbyte = (8 * b4 + 4 * lg) * 2;
            *(short4*)((char*)ldsO + q * 64 + (dbyte ^ ((q & 7) << 3))) = pkv;
        }
    }
    __syncthreads();
    #pragma unroll
    for (int rr = 0; rr < 2; ++rr) {
        int q = tid + rr * 256;
        short* dst = ctx + (size_t)(b * 512 + q) * 128 + h * 32;
        #pragma unroll
        for (int i = 0; i < 8; ++i) {
            short4 part = *(short4*)((char*)ldsO + q * 64 + ((i * 8) ^ ((q & 7) << 3)));
            *(short4*)(dst + i * 4) = part;
        }
    }
}

// ---------------------------------------------------------------------------
// combine: hbuf = hlocal + bn(hin1 + hattn) ; dual f32 + bf16 outputs
// ---------------------------------------------------------------------------
__global__ __launch_bounds__(256)
void combine_kernel(const float* __restrict__ hlocal, const float* __restrict__ hin1,
                    const float* __restrict__ hattn, const float* __restrict__ g,
                    const float* __restrict__ beta, float* __restrict__ outf,
                    short* __restrict__ outb)
{
    int t = blockIdx.x * 256 + threadIdx.x;
    int c = (t & 31) * 4;
    const float rs = 0.9999950000374998f;
    float4 hl = *(const float4*)(hlocal + (size_t)t * 4);
    float4 hi = *(const float4*)(hin1   + (size_t)t * 4);
    float4 ha = *(const float4*)(hattn  + (size_t)t * 4);
    float4 gv = *(const float4*)(g + c);
    float4 bt = *(const float4*)(beta + c);
    float4 o;
    o.x = hl.x + (hi.x + ha.x) * (gv.x * rs) + bt.x;
    o.y = hl.y + (hi.y + ha.y) * (gv.y * rs) + bt.y;
    o.z = hl.z + (hi.z + ha.z) * (gv.z * rs) + bt.z;
    o.w = hl.w + (hi.w + ha.w) * (gv.w * rs) + bt.w;
    *(float4*)(outf + (size_t)t * 4) = o;
    short4 ob; ob.x = f2bs(o.x); ob.y = f2bs(o.y); ob.z = f2bs(o.z); ob.w = f2bs(o.w);
    *(short4*)(outb + (size_t)t * 4) = ob;
}

__global__ __launch_bounds__(256)
void bn_add_kernel(const float* __restrict__ a, const float* __restrict__ b,
                   const float* __restrict__ g, const float* __restrict__ beta,
                   float* __restrict__ out)
{
    int t = blockIdx.x * 256 + threadIdx.x;
    int c = (t & 31) * 4;
    const float rs = 0.9999950000374998f;
    float4 av = *(const float4*)(a + (size_t)t * 4);
    float4 bv = *(const float4*)(b + (size_t)t * 4);
    float4 gv = *(const float4*)(g + c);
    float4 bt = *(const float4*)(beta + c);
    float4 o;
    o.x = (av.x + bv.x) * (gv.x * rs) + bt.x;
    o.y = (av.y + bv.y) * (gv.y * rs) + bt.y;
    o.z = (av.z + bv.z) * (gv.z * rs) + bt.z;
    o.w = (av.w + bv.w) * (gv.w * rs) + bt.w;
    *(float4*)(out + (size_t)t * 4) = o;
}

// ---------------------------------------------------------------------------
extern "C" void kernel_launch(void* const* d_in, const int* in_sizes, int n_in,
                              void* d_out, int out_size, void* d_ws, size_t ws_size,
                              hipStream_t stream)
{
    (void)in_sizes; (void)n_in; (void)out_size; (void)ws_size;

    const float* x    = (const float*)d_in[0];
    const int*   ei   = (const int*)d_in[1];
    const float* Wres = (const float*)d_in[3];
    const float* bres = (const float*)d_in[4];
    const float* Wk   = (const float*)d_in[5];
    const float* bk   = (const float*)d_in[6];
    const float* Wq   = (const float*)d_in[7];
    const float* bq   = (const float*)d_in[8];
    const float* Wv   = (const float*)d_in[9];
    const float* bv   = (const float*)d_in[10];
    const float* Wsk  = (const float*)d_in[11];
    const float* bsk  = (const float*)d_in[12];
    const float* g1l  = (const float*)d_in[13];
    const float* b1l  = (const float*)d_in[14];
    const float* g1a  = (const float*)d_in[15];
    const float* b1a  = (const float*)d_in[16];
    const float* Win  = (const float*)d_in[17];
    const float* bin  = (const float*)d_in[18];
    const float* Wout = (const float*)d_in[19];
    const float* bout = (const float*)d_in[20];
    const float* W1   = (const float*)d_in[21];
    const float* b1   = (const float*)d_in[22];
    const float* W2   = (const float*)d_in[23];
    const float* b2   = (const float*)d_in[24];
    const float* g2   = (const float*)d_in[25];
    const float* b2g  = (const float*)d_in[26];
    float* out = (float*)d_out;

    float* ws = (float*)d_ws;
    // region map (float-slot offsets), NM = 4194304:
    float* hin1f  = ws;                           // [0, NM)          f32
    short* hin1b  = (short*)(ws + NM);            // [NM, 1.5NM)      bf16
    short* xb     = (short*)(ws + NM + NM/2);     // [1.5NM, 2NM)     bf16
    short* kb     = (short*)(ws + 2*NM);          // [2NM, 2.5NM)
    short* qb     = (short*)(ws + 2*NM + NM/2);   // [2.5NM, 3NM)
    short* vb     = (short*)(ws + 3*NM);          // [3NM, 3.5NM)
    short* skipb  = (short*)(ws + 3*NM + NM/2);   // [3.5NM, 4NM)
    float* hlocal = ws + 4*NM;                    // [4NM, 5NM)       f32
    short* wbf    = (short*)(ws + 5*NM);          // 212992 shorts
    int*   deg     = (int*)(ws + 5*NM + 106496);
    int*   offsets = deg + N_NODES;
    int*   cursor  = offsets + N_NODES + 1;
    int*   csr_src = cursor + N_NODES;
    // overlays (lifetimes verified):
    short* qkvb   = (short*)(ws + 2*NM);          // [2NM, 3.5NM) over xb..vb-dead
    short* ctxb   = (short*)(ws + 3*NM + NM/2);   // over skipb (dead post-gather)
    float* hattnf = ws + NM;                      // over hin1b/xb (dead post-in_proj)
    float* hbuff  = ws + 2*NM;                    // over qkvb (dead post-attn)
    short* hbufb  = (short*)(ws + 3*NM);          // over vb/qkv tail (dead)
    short* ff1b   = (short*)(ws + 4*NM);          // over hlocal (dead post-combine)
    float* ff2f   = ws;                           // over hin1f (dead post-combine)

    dim3 blk(256);
    const float qscale = 0.17677669529663687f;    // 1/sqrt(32)

    // --- conversions (x + weights -> bf16) ---
    cvt_kernel<<<dim3(4304), blk, 0, stream>>>(x, Wres, Wk, Wq, Wv, Wsk, Win, Wout,
                                               W1, W2, xb, wbf);

    // --- node-wise projections (bf16 MFMA) ---
    mgemm<1,2><<<dim3(1,256), blk, 0, stream>>>(xb, wbf+0,      bres, hin1f, hin1b, 128, 128, 0, 1.f);
    mgemm<0,1><<<dim3(1,256), blk, 0, stream>>>(xb, wbf+16384,  bk,   nullptr, kb,   128, 128, 0, 1.f);
    mgemm<0,1><<<dim3(1,256), blk, 0, stream>>>(xb, wbf+32768,  bq,   nullptr, qb,   128, 128, 0, 1.f);
    mgemm<0,1><<<dim3(1,256), blk, 0, stream>>>(xb, wbf+49152,  bv,   nullptr, vb,   128, 128, 0, 1.f);
    mgemm<0,1><<<dim3(1,256), blk, 0, stream>>>(xb, wbf+65536,  bsk,  nullptr, skipb,128, 128, 0, 1.f);

    // --- CSR build ---
    hipMemsetAsync((void*)deg, 0, N_NODES * sizeof(int), stream);
    hist_kernel<<<dim3(N_EDGES/256), blk, 0, stream>>>(ei, deg);
    scan_kernel<<<dim3(1), dim3(1024), 0, stream>>>(deg, offsets, cursor);
    scatter_kernel<<<dim3(N_EDGES/256), blk, 0, stream>>>(ei, cursor, csr_src);

    // --- local path: gather + skip + BN fused ---
    gather_local_kernel<<<dim3(N_NODES/4), blk, 0, stream>>>(
        (const unsigned int*)kb, (const unsigned int*)qb, (const unsigned int*)vb,
        (const unsigned int*)skipb, hin1f, offsets, csr_src, g1l, b1l, hlocal);

    // --- global path: in_proj (q pre-scaled), MFMA attention, out_proj ---
    mgemm<0,1><<<dim3(3,256), blk, 0, stream>>>(hin1b, wbf+81920, bin, nullptr, qkvb,
                                                128, 384, 128, qscale);
    attn_mfma<<<dim3(256), blk, 0, stream>>>(qkvb, ctxb);
    mgemm<0,0><<<dim3(1,256), blk, 0, stream>>>(ctxb, wbf+131072, bout, hattnf, nullptr,
                                                128, 128, 0, 1.f);

    // --- combine ---
    combine_kernel<<<dim3(NM/4/256), blk, 0, stream>>>(hlocal, hin1f, hattnf,
                                                       g1a, b1a, hbuff, hbufb);

    // --- FFN ---
    mgemm<1,1><<<dim3(2,256), blk, 0, stream>>>(hbufb, wbf+147456, b1, nullptr, ff1b,
                                                128, 256, 0, 1.f);
    mgemm<0,0><<<dim3(1,256), blk, 0, stream>>>(ff1b, wbf+180224, b2, ff2f, nullptr,
                                                256, 128, 0, 1.f);

    // --- final BN ---
    bn_add_kernel<<<dim3(NM/4/256), blk, 0, stream>>>(hbuff, ff2f, g2, b2g, out);
}

// Round 4
// 271.526 us; speedup vs baseline: 5.0432x; 1.1095x over previous
//
#include <hip/hip_runtime.h>
#include <math.h>

#define N_NODES 32768
#define N_EDGES 524288
#define DIM     128

static constexpr size_t NM = (size_t)N_NODES * DIM;   // 4194304 floats

typedef __attribute__((ext_vector_type(8)))  short bf8;     // 8 bf16
typedef __attribute__((ext_vector_type(4)))  float f32x4;
typedef __attribute__((ext_vector_type(16))) float f32x16;

// float -> bf16 (RNE) bit trick
__device__ __forceinline__ short f2bs(float x) {
    union { float f; unsigned int u; } v; v.f = x;
    unsigned int r = v.u + 0x7fffu + ((v.u >> 16) & 1u);
    return (short)(r >> 16);
}
__device__ __forceinline__ unsigned int pk2(float a, float b) {
    return (unsigned int)(unsigned short)f2bs(a) |
           ((unsigned int)(unsigned short)f2bs(b) << 16);
}
__device__ __forceinline__ float2 bs2f(unsigned int u) {
    union { unsigned int a; float f; } lo, hi;
    lo.a = u << 16; hi.a = u & 0xffff0000u;
    float2 r; r.x = lo.f; r.y = hi.f; return r;
}

// ---------------------------------------------------------------------------
// cvt: x (f32->bf16), 9 weight matrices -> wbf (bf16), 5-bias concat -> bcat
// wbf offsets: Wres 0, Wk 16384, Wq 32768, Wv 49152, Wskip 65536,
//              Win 81920, Wout 131072, W1 147456, W2 180224 (end 212992)
// ---------------------------------------------------------------------------
__global__ __launch_bounds__(256)
void cvt_kernel(const float* __restrict__ x,
                const float* __restrict__ w0, const float* __restrict__ w1,
                const float* __restrict__ w2, const float* __restrict__ w3,
                const float* __restrict__ w4, const float* __restrict__ w5,
                const float* __restrict__ w6, const float* __restrict__ w7,
                const float* __restrict__ w8,
                const float* __restrict__ b0, const float* __restrict__ b1,
                const float* __restrict__ b2, const float* __restrict__ b3,
                const float* __restrict__ b4,
                short* __restrict__ xb, short* __restrict__ wbf,
                float* __restrict__ bcat)
{
    long long t = (long long)blockIdx.x * 256 + threadIdx.x;
    long long i4 = t * 4;
    if (i4 < (long long)NM) {
        float4 v = *(const float4*)(x + i4);
        short4 o; o.x = f2bs(v.x); o.y = f2bs(v.y); o.z = f2bs(v.z); o.w = f2bs(v.w);
        *(short4*)(xb + i4) = o;
    } else {
        int j = (int)(i4 - (long long)NM);
        if (j < 212992) {
            const float* src; int off;
            if      (j <  16384) { src = w0; off = 0; }
            else if (j <  32768) { src = w1; off = 16384; }
            else if (j <  49152) { src = w2; off = 32768; }
            else if (j <  65536) { src = w3; off = 49152; }
            else if (j <  81920) { src = w4; off = 65536; }
            else if (j < 131072) { src = w5; off = 81920; }
            else if (j < 147456) { src = w6; off = 131072; }
            else if (j < 180224) { src = w7; off = 147456; }
            else                 { src = w8; off = 180224; }
            float4 v = *(const float4*)(src + (j - off));
            short4 o; o.x = f2bs(v.x); o.y = f2bs(v.y); o.z = f2bs(v.z); o.w = f2bs(v.w);
            *(short4*)(wbf + j) = o;
        } else if (j < 213632) {
            int jb = j - 212992;                 // 0..639
            int grp = jb >> 7, loc = jb & 127;
            const float* bs = (grp == 0) ? b0 : (grp == 1) ? b1 :
                              (grp == 2) ? b2 : (grp == 3) ? b3 : b4;
            float4 v = *(const float4*)(bs + loc);
            *(float4*)(bcat + jb) = v;
        }
    }
}

// ---------------------------------------------------------------------------
// bf16 MFMA GEMM, 64x128 block tile, 4 waves (2x2), wave tile 32x64,
// K fully unrolled (template). EPI epilogues:
//   0 plain: (acc+bias)[*qscale in col window][relu] -> of?/ob? (Nout stride)
//   1 proj5: N=640 fused projections; blockIdx.x = output group;
//            g0: relu, dual f32+bf16 (hin1); g1..4: bf16 (k,q,v,skip)
//   2 combine: o = aux2 + (aux1 + acc+bias)*gbn*rs + bbn -> of(f32)+ob(bf16)
//   3 bnfinal: o = (aux1 + acc+bias)*gbn*rs + bbn -> of(f32)
// ---------------------------------------------------------------------------
template<int EPI, int RELU, int KT>
__global__ __launch_bounds__(256)
void mgemm(const short* __restrict__ A, const short* __restrict__ Wb,
           const float* __restrict__ bias, int Nout,
           float* __restrict__ of, short* __restrict__ ob,
           short* __restrict__ ob1, short* __restrict__ ob2,
           short* __restrict__ ob3, short* __restrict__ ob4,
           const float* __restrict__ aux1, const float* __restrict__ aux2,
           const float* __restrict__ gbn, const float* __restrict__ bbn,
           int sc_lo, int sc_hi, float qscale)
{
    const int lane = threadIdx.x & 63;
    const int wid  = threadIdx.x >> 6;
    const int m0 = blockIdx.y * 64 + (wid >> 1) * 32;
    const int n0 = blockIdx.x * 128 + (wid & 1) * 64;
    const int lrow = lane & 15;
    const int lk   = (lane >> 4) * 8;
    const float rs = 0.9999950000374998f;     // 1/sqrt(1+1e-5)

    f32x4 acc[2][4] = {};
    const short* Ap = A  + (size_t)(m0 + lrow) * KT + lk;
    const short* Wp = Wb + (size_t)(n0 + lrow) * KT + lk;

    #pragma unroll
    for (int ks = 0; ks < KT; ks += 32) {
        bf8 af[2], wf[4];
        #pragma unroll
        for (int i = 0; i < 2; ++i)
            af[i] = *(const bf8*)(Ap + (size_t)i * 16 * KT + ks);
        #pragma unroll
        for (int j = 0; j < 4; ++j)
            wf[j] = *(const bf8*)(Wp + (size_t)j * 16 * KT + ks);
        #pragma unroll
        for (int i = 0; i < 2; ++i)
            #pragma unroll
            for (int j = 0; j < 4; ++j)
                acc[i][j] = __builtin_amdgcn_mfma_f32_16x16x32_bf16(
                                af[i], wf[j], acc[i][j], 0, 0, 0);
    }

    const int rbase = (lane >> 4) * 4;
    #pragma unroll
    for (int j = 0; j < 4; ++j) {
        int col = n0 + j * 16 + lrow;
        float bcol = bias[col];
        float gsc = 0.f, bsc = 0.f;
        if (EPI == 2 || EPI == 3) { gsc = gbn[col] * rs; bsc = bbn[col]; }
        float sc = 1.0f;
        if (EPI == 0) sc = (col >= sc_lo && col < sc_hi) ? qscale : 1.0f;
        #pragma unroll
        for (int i = 0; i < 2; ++i) {
            #pragma unroll
            for (int r = 0; r < 4; ++r) {
                int row = m0 + i * 16 + rbase + r;
                float v = acc[i][j][r] + bcol;
                if (EPI == 0) {
                    v *= sc;
                    if (RELU) v = fmaxf(v, 0.0f);
                    size_t idx = (size_t)row * Nout + col;
                    if (of) of[idx] = v;
                    if (ob) ob[idx] = f2bs(v);
                } else if (EPI == 1) {
                    int g = blockIdx.x;
                    size_t idx = (size_t)row * 128 + (col & 127);
                    if (g == 0) {
                        v = fmaxf(v, 0.0f);
                        of[idx] = v;
                        ob[idx] = f2bs(v);
                    } else {
                        short* tb = (g == 1) ? ob1 : (g == 2) ? ob2 :
                                    (g == 3) ? ob3 : ob4;
                        tb[idx] = f2bs(v);
                    }
                } else if (EPI == 2) {
                    size_t idx = (size_t)row * 128 + col;
                    float o = aux2[idx] + (aux1[idx] + v) * gsc + bsc;
                    of[idx] = o;
                    ob[idx] = f2bs(o);
                } else {  // EPI == 3
                    size_t idx = (size_t)row * 128 + col;
                    of[idx] = (aux1[idx] + v) * gsc + bsc;
                }
            }
        }
    }
}

// ---------------------------------------------------------------------------
// CSR build: histogram -> scan -> scatter (dst-sorted src list)
// ---------------------------------------------------------------------------
__global__ __launch_bounds__(256)
void hist_kernel(const int* __restrict__ ei, int* __restrict__ deg)
{
    int e = blockIdx.x * 256 + threadIdx.x;
    atomicAdd(&deg[ei[N_EDGES + e]], 1);
}

__global__ __launch_bounds__(1024)
void scan_kernel(const int* __restrict__ deg, int* __restrict__ offsets,
                 int* __restrict__ cursor)
{
    __shared__ int bufA[1024];
    __shared__ int bufB[1024];
    const int t = threadIdx.x;
    const int base = t * 32;

    int local[32];
    int run = 0;
    #pragma unroll
    for (int j = 0; j < 32; ++j) { local[j] = run; run += deg[base + j]; }

    int* src = bufA;
    int* dst = bufB;
    src[t] = run;
    __syncthreads();
    for (int off = 1; off < 1024; off <<= 1) {
        int v = src[t] + ((t >= off) ? src[t - off] : 0);
        dst[t] = v;
        __syncthreads();
        int* tmp = src; src = dst; dst = tmp;
    }
    int blockbase = (t == 0) ? 0 : src[t - 1];

    #pragma unroll
    for (int j = 0; j < 32; ++j) {
        int v = blockbase + local[j];
        offsets[base + j] = v;
        cursor[base + j]  = v;
    }
    if (t == 1023) offsets[N_NODES] = src[1023];
}

__global__ __launch_bounds__(256)
void scatter_kernel(const int* __restrict__ ei, int* __restrict__ cursor,
                    int* __restrict__ csr_src)
{
    int e = blockIdx.x * 256 + threadIdx.x;
    int d = ei[N_EDGES + e];
    int pos = atomicAdd(&cursor[d], 1);
    csr_src[pos] = ei[e];
}

// ---------------------------------------------------------------------------
// Gather aggregation (bf16) + skip + BN fused. One wave per node, 2-edge unroll,
// v_rcp_f32 sigmoid. No atomics.
// ---------------------------------------------------------------------------
__global__ __launch_bounds__(256)
void gather_local_kernel(const unsigned int* __restrict__ kb,
                         const unsigned int* __restrict__ qb,
                         const unsigned int* __restrict__ vb,
                         const unsigned int* __restrict__ skipb,
                         const unsigned int* __restrict__ hin1b,
                         const int* __restrict__ offsets, const int* __restrict__ csr_src,
                         const float* __restrict__ g, const float* __restrict__ beta,
                         float* __restrict__ hlocal)
{
    const int d    = blockIdx.x * 4 + (threadIdx.x >> 6);
    const int lane = threadIdx.x & 63;          // owns cols 2*lane, 2*lane+1
    const float rs = 0.9999950000374998f;       // 1/sqrt(1+1e-5)

    float2 k2 = bs2f(kb[(size_t)d * 64 + lane]);
    int i = offsets[d];
    const int end = offsets[d + 1];

    float ax = 0.f, ay = 0.f, cx = 0.f, cy = 0.f;
    for (; i + 2 <= end; i += 2) {
        int s0 = csr_src[i];
        int s1 = csr_src[i + 1];
        unsigned int uq0 = qb[(size_t)s0 * 64 + lane];
        unsigned int uv0 = vb[(size_t)s0 * 64 + lane];
        unsigned int uq1 = qb[(size_t)s1 * 64 + lane];
        unsigned int uv1 = vb[(size_t)s1 * 64 + lane];
        float2 q0 = bs2f(uq0), v0 = bs2f(uv0);
        float2 q1 = bs2f(uq1), v1 = bs2f(uv1);
        ax += v0.x * __builtin_amdgcn_rcpf(1.0f + __expf(-(k2.x + q0.x)));
        ay += v0.y * __builtin_amdgcn_rcpf(1.0f + __expf(-(k2.y + q0.y)));
        cx += v1.x * __builtin_amdgcn_rcpf(1.0f + __expf(-(k2.x + q1.x)));
        cy += v1.y * __builtin_amdgcn_rcpf(1.0f + __expf(-(k2.y + q1.y)));
    }
    if (i < end) {
        int s0 = csr_src[i];
        float2 q0 = bs2f(qb[(size_t)s0 * 64 + lane]);
        float2 v0 = bs2f(vb[(size_t)s0 * 64 + lane]);
        ax += v0.x * __builtin_amdgcn_rcpf(1.0f + __expf(-(k2.x + q0.x)));
        ay += v0.y * __builtin_amdgcn_rcpf(1.0f + __expf(-(k2.y + q0.y)));
    }
    ax += cx; ay += cy;

    float2 sk = bs2f(skipb[(size_t)d * 64 + lane]);
    float2 hi = bs2f(hin1b[(size_t)d * 64 + lane]);
    float2 gv = *(const float2*)(g + lane * 2);
    float2 bt = *(const float2*)(beta + lane * 2);
    float2 o;
    o.x = (hi.x + sk.x + ax) * (gv.x * rs) + bt.x;
    o.y = (hi.y + sk.y + ay) * (gv.y * rs) + bt.y;
    *(float2*)(hlocal + (size_t)d * DIM + lane * 2) = o;
}

// ---------------------------------------------------------------------------
// MFMA flash attention. 512 blocks = (b, h, half); 4 waves, 64 q-rows each.
// K in LDS (80B row stride, conflict-spread); V^T in LDS (swizzled).
// ---------------------------------------------------------------------------
__device__ __forceinline__ void lswap(unsigned int& X, unsigned int& Y, bool hi) {
    unsigned int Xs = (unsigned int)__shfl_xor((int)X, 32);
    unsigned int Ys = (unsigned int)__shfl_xor((int)Y, 32);
    unsigned int Xn = hi ? Ys : X;
    unsigned int Yn = hi ? Y  : Xs;
    X = Xn; Y = Yn;
}

__global__ __launch_bounds__(256)
void attn_mfma(const short* __restrict__ qkv, short* __restrict__ ctx)
{
    __shared__ __align__(16) short ldsK[512 * 40];    // 40 KB (stride 80B), reused as O
    __shared__ __align__(16) short ldsVt[32 * 512];   // 32 KB, swizzled

    const int blk  = blockIdx.x;         // B*H*2 = 512
    const int half = blk & 1;
    const int h    = (blk >> 1) & 3;
    const int b    = blk >> 3;
    const int tid  = threadIdx.x;
    const int lane = tid & 63;
    const int wid  = tid >> 6;
    const int lq = lane & 31;
    const int lg = lane >> 5;
    const size_t gbase = (size_t)(b * 512) * 384 + h * 32;

    // --- stage K rows: ldsK[key*40 + part*8] ---
    #pragma unroll
    for (int i = 0; i < 8; ++i) {
        int c = tid + i * 256;              // 0..2047
        int key = c >> 2, part = c & 3;
        bf8 v = *(const bf8*)(qkv + gbase + (size_t)key * 384 + 128 + part * 8);
        *(bf8*)(ldsK + key * 40 + part * 8) = v;
    }
    // --- stage V transposed: ldsVt row d, byte (key*2) ^ ((d&7)<<4) ---
    {
        int p = tid;                        // key pair (2p, 2p+1)
        const short* v0 = qkv + gbase + (size_t)(2 * p) * 384 + 256;
        const short* v1 = v0 + 384;
        bf8 r0[4], r1[4];
        #pragma unroll
        for (int i = 0; i < 4; ++i) { r0[i] = *(const bf8*)(v0 + i * 8);
                                      r1[i] = *(const bf8*)(v1 + i * 8); }
        #pragma unroll
        for (int d = 0; d < 32; ++d) {
            unsigned int w = ((unsigned int)(unsigned short)r0[d >> 3][d & 7]) |
                             (((unsigned int)(unsigned short)r1[d >> 3][d & 7]) << 16);
            *(unsigned int*)((char*)ldsVt + d * 1024 + ((4 * p) ^ ((d & 7) << 4))) = w;
        }
    }
    // --- Q fragments in registers (q pre-scaled at in_proj) ---
    const int qoff = half * 256 + wid * 64;
    bf8 qf[2][2];
    #pragma unroll
    for (int qg = 0; qg < 2; ++qg)
        #pragma unroll
        for (int kh = 0; kh < 2; ++kh)
            qf[qg][kh] = *(const bf8*)(qkv + gbase +
                           (size_t)(qoff + qg * 32 + lq) * 384 + kh * 16 + lg * 8);
    __syncthreads();

    const f32x16 Z16 = {0.f,0.f,0.f,0.f,0.f,0.f,0.f,0.f,0.f,0.f,0.f,0.f,0.f,0.f,0.f,0.f};
    f32x16 o[2] = {Z16, Z16};
    float mreg[2] = {-1e30f, -1e30f};
    float lreg[2] = {0.f, 0.f};
    const bool hiw = (lg != 0);

    for (int kt = 0; kt < 16; ++kt) {
        bf8 ak[2], vt[2];
        #pragma unroll
        for (int kh = 0; kh < 2; ++kh) {
            ak[kh] = *(const bf8*)(ldsK + (kt * 32 + lq) * 40 + kh * 16 + lg * 8);
            int kbyte = (kt * 32 + kh * 16 + lg * 8) * 2;
            vt[kh] = *(const bf8*)((const char*)ldsVt + lq * 1024 +
                                   (kbyte ^ ((lq & 7) << 4)));
        }
        #pragma unroll
        for (int qg = 0; qg < 2; ++qg) {
            f32x16 s = Z16;
            s = __builtin_amdgcn_mfma_f32_32x32x16_bf16(ak[0], qf[qg][0], s, 0, 0, 0);
            s = __builtin_amdgcn_mfma_f32_32x32x16_bf16(ak[1], qf[qg][1], s, 0, 0, 0);
            float mt = s[0];
            #pragma unroll
            for (int r = 1; r < 16; ++r) mt = fmaxf(mt, s[r]);
            mt = fmaxf(mt, __shfl_xor(mt, 32));
            float mnew = fmaxf(mreg[qg], mt);
            float corr = __expf(mreg[qg] - mnew);
            mreg[qg] = mnew;
            float p[16]; float ps = 0.f;
            #pragma unroll
            for (int r = 0; r < 16; ++r) { p[r] = __expf(s[r] - mnew); ps += p[r]; }
            ps += __shfl_xor(ps, 32);
            lreg[qg] = lreg[qg] * corr + ps;
            #pragma unroll
            for (int r = 0; r < 16; ++r) o[qg][r] *= corr;
            unsigned int w0 = pk2(p[0],  p[1]),  w1 = pk2(p[2],  p[3]);
            unsigned int w2 = pk2(p[4],  p[5]),  w3 = pk2(p[6],  p[7]);
            unsigned int w4 = pk2(p[8],  p[9]),  w5 = pk2(p[10], p[11]);
            unsigned int w6 = pk2(p[12], p[13]), w7 = pk2(p[14], p[15]);
            lswap(w0, w2, hiw); lswap(w1, w3, hiw);
            lswap(w4, w6, hiw); lswap(w5, w7, hiw);
            union { unsigned int u[4]; bf8 v; } P0, P1;
            P0.u[0] = w0; P0.u[1] = w1; P0.u[2] = w2; P0.u[3] = w3;
            P1.u[0] = w4; P1.u[1] = w5; P1.u[2] = w6; P1.u[3] = w7;
            o[qg] = __builtin_amdgcn_mfma_f32_32x32x16_bf16(vt[0], P0.v, o[qg], 0, 0, 0);
            o[qg] = __builtin_amdgcn_mfma_f32_32x32x16_bf16(vt[1], P1.v, o[qg], 0, 0, 0);
        }
    }

    // --- epilogue: O^T regs -> LDS (swizzled) -> coalesced global bf16 ---
    __syncthreads();
    short* ldsO = ldsK;                    // [256 q][32 d], byte ^ ((q&7)<<3)
    #pragma unroll
    for (int qg = 0; qg < 2; ++qg) {
        float inv = 1.0f / lreg[qg];
        int ql = wid * 64 + qg * 32 + lq;  // 0..255
        #pragma unroll
        for (int b4 = 0; b4 < 4; ++b4) {   // regs 4*b4..+3 -> d = 8*b4 + 4*lg ..+3
            short4 pkv;
            pkv.x = f2bs(o[qg][b4 * 4 + 0] * inv);
            pkv.y = f2bs(o[qg][b4 * 4 + 1] * inv);
            pkv.z = f2bs(o[qg][b4 * 4 + 2] * inv);
            pkv.w = f2bs(o[qg][b4 * 4 + 3] * inv);
            int dbyte = (8 * b4 + 4 * lg) * 2;
            *(short4*)((char*)ldsO + ql * 64 + (dbyte ^ ((ql & 7) << 3))) = pkv;
        }
    }
    __syncthreads();
    {
        int ql = tid;                       // 0..255
        short* dst = ctx + (size_t)(b * 512 + half * 256 + ql) * 128 + h * 32;
        #pragma unroll
        for (int i = 0; i < 8; ++i) {
            short4 part = *(short4*)((char*)ldsO + ql * 64 + ((i * 8) ^ ((ql & 7) << 3)));
            *(short4*)(dst + i * 4) = part;
        }
    }
}

// ---------------------------------------------------------------------------
extern "C" void kernel_launch(void* const* d_in, const int* in_sizes, int n_in,
                              void* d_out, int out_size, void* d_ws, size_t ws_size,
                              hipStream_t stream)
{
    (void)in_sizes; (void)n_in; (void)out_size; (void)ws_size;

    const float* x    = (const float*)d_in[0];
    const int*   ei   = (const int*)d_in[1];
    const float* Wres = (const float*)d_in[3];
    const float* bres = (const float*)d_in[4];
    const float* Wk   = (const float*)d_in[5];
    const float* bk   = (const float*)d_in[6];
    const float* Wq   = (const float*)d_in[7];
    const float* bq   = (const float*)d_in[8];
    const float* Wv   = (const float*)d_in[9];
    const float* bv   = (const float*)d_in[10];
    const float* Wsk  = (const float*)d_in[11];
    const float* bsk  = (const float*)d_in[12];
    const float* g1l  = (const float*)d_in[13];
    const float* b1l  = (const float*)d_in[14];
    const float* g1a  = (const float*)d_in[15];
    const float* b1a  = (const float*)d_in[16];
    const float* Win  = (const float*)d_in[17];
    const float* bin  = (const float*)d_in[18];
    const float* Wout = (const float*)d_in[19];
    const float* bout = (const float*)d_in[20];
    const float* W1   = (const float*)d_in[21];
    const float* b1   = (const float*)d_in[22];
    const float* W2   = (const float*)d_in[23];
    const float* b2   = (const float*)d_in[24];
    const float* g2   = (const float*)d_in[25];
    const float* b2g  = (const float*)d_in[26];
    float* out = (float*)d_out;

    float* ws = (float*)d_ws;
    // region map (float-slot offsets), NM = 4194304:
    float* hin1f  = ws;                           // [0, NM)          f32
    short* hin1b  = (short*)(ws + NM);            // [NM, 1.5NM)      bf16
    short* xb     = (short*)(ws + NM + NM/2);     // [1.5NM, 2NM)     bf16
    short* kb     = (short*)(ws + 2*NM);          // [2NM, 2.5NM)
    short* qb     = (short*)(ws + 2*NM + NM/2);   // [2.5NM, 3NM)
    short* vb     = (short*)(ws + 3*NM);          // [3NM, 3.5NM)
    short* skipb  = (short*)(ws + 3*NM + NM/2);   // [3.5NM, 4NM)
    float* hlocal = ws + 4*NM;                    // [4NM, 5NM)       f32
    short* wbf    = (short*)(ws + 5*NM);          // 212992 shorts
    int*   deg     = (int*)(ws + 5*NM + 106496);
    int*   offsets = deg + N_NODES;
    int*   cursor  = offsets + N_NODES + 1;
    int*   csr_src = cursor + N_NODES;
    float* bcat    = (float*)(csr_src + N_EDGES); // [640] f32
    // overlays (lifetimes verified):
    short* qkvb   = (short*)(ws + 2*NM);          // [2NM, 3.5NM) over kb/qb/vb (dead post-gather)
    short* ctxb   = (short*)(ws + 3*NM + NM/2);   // over skipb (dead post-gather)
    float* hbuff  = ws + 2*NM;                    // over qkvb (dead post-attn)   f32
    short* hbufb  = (short*)(ws + 3*NM);          // over qkvb tail (dead post-attn)
    short* ff1b   = (short*)(ws + 4*NM);          // over hlocal (dead post-out_proj)

    dim3 blk(256);
    const float qscale = 0.17677669529663687f;    // 1/sqrt(32)

    // --- conversions ---
    cvt_kernel<<<dim3(4305), blk, 0, stream>>>(x, Wres, Wk, Wq, Wv, Wsk, Win, Wout,
                                               W1, W2, bres, bk, bq, bv, bsk,
                                               xb, wbf, bcat);

    // --- CSR build ---
    hipMemsetAsync((void*)deg, 0, N_NODES * sizeof(int), stream);
    hist_kernel<<<dim3(N_EDGES/256), blk, 0, stream>>>(ei, deg);
    scan_kernel<<<dim3(1), dim3(1024), 0, stream>>>(deg, offsets, cursor);
    scatter_kernel<<<dim3(N_EDGES/256), blk, 0, stream>>>(ei, cursor, csr_src);

    // --- fused 5-way projection: [hin1 | k | q | v | skip], N=640 ---
    mgemm<1,0,128><<<dim3(5,512), blk, 0, stream>>>(
        xb, wbf, bcat, 640, hin1f, hin1b, kb, qb, vb, skipb,
        nullptr, nullptr, nullptr, nullptr, 0, 0, 1.f);

    // --- local path: gather + skip + BN fused ---
    gather_local_kernel<<<dim3(N_NODES/4), blk, 0, stream>>>(
        (const unsigned int*)kb, (const unsigned int*)qb, (const unsigned int*)vb,
        (const unsigned int*)skipb, (const unsigned int*)hin1b,
        offsets, csr_src, g1l, b1l, hlocal);

    // --- global path: in_proj (q pre-scaled), MFMA attention ---
    mgemm<0,0,128><<<dim3(3,512), blk, 0, stream>>>(
        hin1b, wbf+81920, bin, 384, nullptr, qkvb,
        nullptr, nullptr, nullptr, nullptr, nullptr, nullptr, nullptr, nullptr,
        0, 128, qscale);
    attn_mfma<<<dim3(512), blk, 0, stream>>>(qkvb, ctxb);

    // --- out_proj + combine fused: hbuf = hlocal + bn(hin1 + attnout) ---
    mgemm<2,0,128><<<dim3(1,512), blk, 0, stream>>>(
        ctxb, wbf+131072, bout, 128, hbuff, hbufb,
        nullptr, nullptr, nullptr, nullptr, hin1f, hlocal, g1a, b1a, 0, 0, 1.f);

    // --- FFN ---
    mgemm<0,1,128><<<dim3(2,512), blk, 0, stream>>>(
        hbufb, wbf+147456, b1, 256, nullptr, ff1b,
        nullptr, nullptr, nullptr, nullptr, nullptr, nullptr, nullptr, nullptr,
        0, 0, 1.f);
    mgemm<3,0,256><<<dim3(1,512), blk, 0, stream>>>(
        ff1b, wbf+180224, b2, 128, out, nullptr,
        nullptr, nullptr, nullptr, nullptr, hbuff, nullptr, g2, b2g, 0, 0, 1.f);
}

// Round 6
// 237.055 us; speedup vs baseline: 5.7765x; 1.1454x over previous
//
#include <hip/hip_runtime.h>
#include <math.h>

#define N_NODES 32768
#define N_EDGES 524288
#define DIM     128

static constexpr size_t NM = (size_t)N_NODES * DIM;   // 4194304

typedef __attribute__((ext_vector_type(8)))  short bf8;     // 8 bf16
typedef __attribute__((ext_vector_type(4)))  float f32x4;
typedef __attribute__((ext_vector_type(16))) float f32x16;

__device__ __forceinline__ short f2bs(float x) {
    union { float f; unsigned int u; } v; v.f = x;
    unsigned int r = v.u + 0x7fffu + ((v.u >> 16) & 1u);
    return (short)(r >> 16);
}
__device__ __forceinline__ unsigned int pk2(float a, float b) {
    return (unsigned int)(unsigned short)f2bs(a) |
           ((unsigned int)(unsigned short)f2bs(b) << 16);
}
__device__ __forceinline__ float2 bs2f(unsigned int u) {
    union { unsigned int a; float f; } lo, hi;
    lo.a = u << 16; hi.a = u & 0xffff0000u;
    float2 r; r.x = lo.f; r.y = hi.f; return r;
}
__device__ __forceinline__ float bs1f(short s) {
    union { unsigned int a; float f; } t;
    t.a = ((unsigned int)(unsigned short)s) << 16; return t.f;
}

// ---------------------------------------------------------------------------
// k1: cvt + zero-deg. x->bf16, 9 weights->wbf(bf16), 5-bias concat->bcat, deg=0
// wbf short-offsets: Wres 0, Wk 16384, Wq 32768, Wv 49152, Wskip 65536,
//                    Win 81920, Wout 131072, W1 147456, W2 180224 (end 212992)
// ---------------------------------------------------------------------------
__global__ __launch_bounds__(256)
void cvt_zero_kernel(const float* __restrict__ x,
                     const float* __restrict__ w0, const float* __restrict__ w1,
                     const float* __restrict__ w2, const float* __restrict__ w3,
                     const float* __restrict__ w4, const float* __restrict__ w5,
                     const float* __restrict__ w6, const float* __restrict__ w7,
                     const float* __restrict__ w8,
                     const float* __restrict__ b0, const float* __restrict__ b1,
                     const float* __restrict__ b2, const float* __restrict__ b3,
                     const float* __restrict__ b4,
                     short* __restrict__ xb, short* __restrict__ wbf,
                     float* __restrict__ bcat, int* __restrict__ deg)
{
    if (blockIdx.x >= 4305) {
        int t = (blockIdx.x - 4305) * 256 + threadIdx.x;   // 0..8191
        ((int4*)deg)[t] = make_int4(0, 0, 0, 0);           // 32768 ints
        return;
    }
    long long t = (long long)blockIdx.x * 256 + threadIdx.x;
    long long i4 = t * 4;
    if (i4 < (long long)NM) {
        float4 v = *(const float4*)(x + i4);
        short4 o; o.x = f2bs(v.x); o.y = f2bs(v.y); o.z = f2bs(v.z); o.w = f2bs(v.w);
        *(short4*)(xb + i4) = o;
    } else {
        int j = (int)(i4 - (long long)NM);
        if (j < 212992) {
            const float* src; int off;
            if      (j <  16384) { src = w0; off = 0; }
            else if (j <  32768) { src = w1; off = 16384; }
            else if (j <  49152) { src = w2; off = 32768; }
            else if (j <  65536) { src = w3; off = 49152; }
            else if (j <  81920) { src = w4; off = 65536; }
            else if (j < 131072) { src = w5; off = 81920; }
            else if (j < 147456) { src = w6; off = 131072; }
            else if (j < 180224) { src = w7; off = 147456; }
            else                 { src = w8; off = 180224; }
            float4 v = *(const float4*)(src + (j - off));
            short4 o; o.x = f2bs(v.x); o.y = f2bs(v.y); o.z = f2bs(v.z); o.w = f2bs(v.w);
            *(short4*)(wbf + j) = o;
        } else if (j < 213632) {
            int jb = j - 212992;                 // 0..639
            int grp = jb >> 7, loc = jb & 127;
            const float* bs = (grp == 0) ? b0 : (grp == 1) ? b1 :
                              (grp == 2) ? b2 : (grp == 3) ? b3 : b4;
            float4 v = *(const float4*)(bs + loc);
            *(float4*)(bcat + jb) = v;
        }
    }
}

// ---------------------------------------------------------------------------
// k2: proj5 (fused x-projections, 5 groups) + hist tail blocks.
// blocks 0..2559: GEMM (g = bid/512, my = bid%512); 2560..4607: histogram.
// g0: relu->hin1b; g1: k; g2: q->qv[2c]; g3: v->qv[2c+1]; g4: skipb.
// ---------------------------------------------------------------------------
__global__ __launch_bounds__(256)
void proj5_hist_kernel(const short* __restrict__ xb, const short* __restrict__ wbf,
                       const float* __restrict__ bcat, const int* __restrict__ ei,
                       short* __restrict__ hin1b, short* __restrict__ kbv,
                       short* __restrict__ qvb, short* __restrict__ skipb,
                       int* __restrict__ deg)
{
    const int bid = blockIdx.x;
    if (bid >= 2560) {
        int e = (bid - 2560) * 256 + threadIdx.x;
        atomicAdd(&deg[ei[N_EDGES + e]], 1);
        return;
    }
    const int g  = bid / 512;
    const int my = bid % 512;
    const int lane = threadIdx.x & 63;
    const int wid  = threadIdx.x >> 6;
    const int m0 = my * 64 + (wid >> 1) * 32;
    const int n0 = (wid & 1) * 64;
    const int lrow = lane & 15;
    const int lk   = (lane >> 4) * 8;

    f32x4 acc[2][4] = {};
    const short* Ap = xb + (size_t)(m0 + lrow) * 128 + lk;
    const short* Wp = wbf + g * 16384 + (size_t)(n0 + lrow) * 128 + lk;
    #pragma unroll
    for (int ks = 0; ks < 128; ks += 32) {
        bf8 af[2], wf[4];
        af[0] = *(const bf8*)(Ap + ks);
        af[1] = *(const bf8*)(Ap + 16 * 128 + ks);
        #pragma unroll
        for (int j = 0; j < 4; ++j) wf[j] = *(const bf8*)(Wp + (size_t)j * 16 * 128 + ks);
        #pragma unroll
        for (int i = 0; i < 2; ++i)
            #pragma unroll
            for (int j = 0; j < 4; ++j)
                acc[i][j] = __builtin_amdgcn_mfma_f32_16x16x32_bf16(af[i], wf[j], acc[i][j], 0, 0, 0);
    }
    const int rbase = (lane >> 4) * 4;
    #pragma unroll
    for (int j = 0; j < 4; ++j) {
        int col = n0 + j * 16 + lrow;                 // 0..127
        float bcol = bcat[g * 128 + col];
        #pragma unroll
        for (int i = 0; i < 2; ++i)
            #pragma unroll
            for (int r = 0; r < 4; ++r) {
                int row = m0 + i * 16 + rbase + r;
                float v = acc[i][j][r] + bcol;
                if (g == 0)      { v = fmaxf(v, 0.f); hin1b[(size_t)row * 128 + col] = f2bs(v); }
                else if (g == 1) kbv[(size_t)row * 128 + col] = f2bs(v);
                else if (g == 2) qvb[(size_t)row * 256 + col * 2] = f2bs(v);
                else if (g == 3) qvb[(size_t)row * 256 + col * 2 + 1] = f2bs(v);
                else             skipb[(size_t)row * 128 + col] = f2bs(v);
            }
    }
}

// ---------------------------------------------------------------------------
// k3: scan
// ---------------------------------------------------------------------------
__global__ __launch_bounds__(1024)
void scan_kernel(const int* __restrict__ deg, int* __restrict__ offsets,
                 int* __restrict__ cursor)
{
    __shared__ int bufA[1024];
    __shared__ int bufB[1024];
    const int t = threadIdx.x;
    const int base = t * 32;

    int local[32];
    int run = 0;
    #pragma unroll
    for (int j = 0; j < 32; ++j) { local[j] = run; run += deg[base + j]; }

    int* src = bufA;
    int* dst = bufB;
    src[t] = run;
    __syncthreads();
    for (int off = 1; off < 1024; off <<= 1) {
        int v = src[t] + ((t >= off) ? src[t - off] : 0);
        dst[t] = v;
        __syncthreads();
        int* tmp = src; src = dst; dst = tmp;
    }
    int blockbase = (t == 0) ? 0 : src[t - 1];

    #pragma unroll
    for (int j = 0; j < 32; ++j) {
        int v = blockbase + local[j];
        offsets[base + j] = v;
        cursor[base + j]  = v;
    }
    if (t == 1023) offsets[N_NODES] = src[1023];
}

// ---------------------------------------------------------------------------
// k4: in_proj GEMM (qkv, q-cols pre-scaled) + scatter tail blocks.
// blocks 0..1535: GEMM (gx = bid%3, my = bid/3); 1536..3583: scatter.
// ---------------------------------------------------------------------------
__global__ __launch_bounds__(256)
void inproj_scatter_kernel(const short* __restrict__ hin1b, const short* __restrict__ wbf,
                           const float* __restrict__ bin, const int* __restrict__ ei,
                           int* __restrict__ cursor, int* __restrict__ csr_src,
                           short* __restrict__ qkvb, float qscale)
{
    const int bid = blockIdx.x;
    if (bid >= 1536) {
        int e = (bid - 1536) * 256 + threadIdx.x;
        int d = ei[N_EDGES + e];
        int pos = atomicAdd(&cursor[d], 1);
        csr_src[pos] = ei[e];
        return;
    }
    const int gx = bid % 3;
    const int my = bid / 3;
    const int lane = threadIdx.x & 63;
    const int wid  = threadIdx.x >> 6;
    const int m0 = my * 64 + (wid >> 1) * 32;
    const int n0 = (wid & 1) * 64;
    const int lrow = lane & 15;
    const int lk   = (lane >> 4) * 8;

    f32x4 acc[2][4] = {};
    const short* Ap = hin1b + (size_t)(m0 + lrow) * 128 + lk;
    const short* Wp = wbf + 81920 + (size_t)(gx * 128 + n0 + lrow) * 128 + lk;
    #pragma unroll
    for (int ks = 0; ks < 128; ks += 32) {
        bf8 af[2], wf[4];
        af[0] = *(const bf8*)(Ap + ks);
        af[1] = *(const bf8*)(Ap + 16 * 128 + ks);
        #pragma unroll
        for (int j = 0; j < 4; ++j) wf[j] = *(const bf8*)(Wp + (size_t)j * 16 * 128 + ks);
        #pragma unroll
        for (int i = 0; i < 2; ++i)
            #pragma unroll
            for (int j = 0; j < 4; ++j)
                acc[i][j] = __builtin_amdgcn_mfma_f32_16x16x32_bf16(af[i], wf[j], acc[i][j], 0, 0, 0);
    }
    const int rbase = (lane >> 4) * 4;
    #pragma unroll
    for (int j = 0; j < 4; ++j) {
        int col = gx * 128 + n0 + j * 16 + lrow;      // 0..383
        float bcol = bin[col];
        float sc = (col < 128) ? qscale : 1.0f;
        #pragma unroll
        for (int i = 0; i < 2; ++i)
            #pragma unroll
            for (int r = 0; r < 4; ++r) {
                int row = m0 + i * 16 + rbase + r;
                float v = (acc[i][j][r] + bcol) * sc;
                qkvb[(size_t)row * 384 + col] = f2bs(v);
            }
    }
}

// ---------------------------------------------------------------------------
// k5: gather aggregation: qv interleaved (one 8B load per edge per lane),
// 4-edge unroll, rcp sigmoid, fused skip + BN, bf16 out. No atomics.
// ---------------------------------------------------------------------------
__global__ __launch_bounds__(256)
void gather_local_kernel(const unsigned int* __restrict__ kbu,
                         const uint2* __restrict__ qvu,
                         const unsigned int* __restrict__ skipu,
                         const unsigned int* __restrict__ hin1u,
                         const int* __restrict__ offsets, const int* __restrict__ csr_src,
                         const float* __restrict__ g, const float* __restrict__ beta,
                         unsigned int* __restrict__ hlocal_u)
{
    const int d    = blockIdx.x * 4 + (threadIdx.x >> 6);
    const int lane = threadIdx.x & 63;          // owns cols 2l, 2l+1
    const float rs = 0.9999950000374998f;       // 1/sqrt(1+1e-5)

    float2 k2 = bs2f(kbu[(size_t)d * 64 + lane]);
    int i = offsets[d];
    const int end = offsets[d + 1];

    float ax = 0.f, ay = 0.f, cx = 0.f, cy = 0.f;
    for (; i + 4 <= end; i += 4) {
        int s0 = csr_src[i],     s1 = csr_src[i + 1];
        int s2 = csr_src[i + 2], s3 = csr_src[i + 3];
        uint2 w0 = qvu[(size_t)s0 * 64 + lane];
        uint2 w1 = qvu[(size_t)s1 * 64 + lane];
        uint2 w2 = qvu[(size_t)s2 * 64 + lane];
        uint2 w3 = qvu[(size_t)s3 * 64 + lane];
        float2 p0 = bs2f(w0.x), p1 = bs2f(w0.y);   // (q,v) col 2l / 2l+1
        float2 p2 = bs2f(w1.x), p3 = bs2f(w1.y);
        float2 p4 = bs2f(w2.x), p5 = bs2f(w2.y);
        float2 p6 = bs2f(w3.x), p7 = bs2f(w3.y);
        ax += p0.y * __builtin_amdgcn_rcpf(1.0f + __expf(-(k2.x + p0.x)));
        ay += p1.y * __builtin_amdgcn_rcpf(1.0f + __expf(-(k2.y + p1.x)));
        cx += p2.y * __builtin_amdgcn_rcpf(1.0f + __expf(-(k2.x + p2.x)));
        cy += p3.y * __builtin_amdgcn_rcpf(1.0f + __expf(-(k2.y + p3.x)));
        ax += p4.y * __builtin_amdgcn_rcpf(1.0f + __expf(-(k2.x + p4.x)));
        ay += p5.y * __builtin_amdgcn_rcpf(1.0f + __expf(-(k2.y + p5.x)));
        cx += p6.y * __builtin_amdgcn_rcpf(1.0f + __expf(-(k2.x + p6.x)));
        cy += p7.y * __builtin_amdgcn_rcpf(1.0f + __expf(-(k2.y + p7.x)));
    }
    for (; i < end; ++i) {
        int s0 = csr_src[i];
        uint2 w0 = qvu[(size_t)s0 * 64 + lane];
        float2 p0 = bs2f(w0.x), p1 = bs2f(w0.y);
        ax += p0.y * __builtin_amdgcn_rcpf(1.0f + __expf(-(k2.x + p0.x)));
        ay += p1.y * __builtin_amdgcn_rcpf(1.0f + __expf(-(k2.y + p1.x)));
    }
    ax += cx; ay += cy;

    float2 sk = bs2f(skipu[(size_t)d * 64 + lane]);
    float2 hi = bs2f(hin1u[(size_t)d * 64 + lane]);
    float2 gv = *(const float2*)(g + lane * 2);
    float2 bt = *(const float2*)(beta + lane * 2);
    float ox = (hi.x + sk.x + ax) * (gv.x * rs) + bt.x;
    float oy = (hi.y + sk.y + ay) * (gv.y * rs) + bt.y;
    hlocal_u[(size_t)d * 64 + lane] = pk2(ox, oy);
}

// ---------------------------------------------------------------------------
// k6: MFMA flash attention. 512 blocks = (b, h, half); 4 waves, 64 q-rows each.
// Defer-max (THR=8), max3-shaped reductions.
// ---------------------------------------------------------------------------
__device__ __forceinline__ void lswap(unsigned int& X, unsigned int& Y, bool hi) {
    unsigned int Xs = (unsigned int)__shfl_xor((int)X, 32);
    unsigned int Ys = (unsigned int)__shfl_xor((int)Y, 32);
    unsigned int Xn = hi ? Ys : X;
    unsigned int Yn = hi ? Y  : Xs;
    X = Xn; Y = Yn;
}

__global__ __launch_bounds__(256)
void attn_mfma(const short* __restrict__ qkv, short* __restrict__ ctx)
{
    __shared__ __align__(16) short ldsK[512 * 40];    // 40 KB, reused as O
    __shared__ __align__(16) short ldsVt[32 * 512];   // 32 KB, swizzled

    const int blk  = blockIdx.x;         // B*H*2 = 512
    const int half = blk & 1;
    const int h    = (blk >> 1) & 3;
    const int b    = blk >> 3;
    const int tid  = threadIdx.x;
    const int lane = tid & 63;
    const int wid  = tid >> 6;
    const int lq = lane & 31;
    const int lg = lane >> 5;
    const size_t gbase = (size_t)(b * 512) * 384 + h * 32;

    #pragma unroll
    for (int i = 0; i < 8; ++i) {
        int c = tid + i * 256;
        int key = c >> 2, part = c & 3;
        bf8 v = *(const bf8*)(qkv + gbase + (size_t)key * 384 + 128 + part * 8);
        *(bf8*)(ldsK + key * 40 + part * 8) = v;
    }
    {
        int p = tid;
        const short* v0 = qkv + gbase + (size_t)(2 * p) * 384 + 256;
        const short* v1 = v0 + 384;
        bf8 r0[4], r1[4];
        #pragma unroll
        for (int i = 0; i < 4; ++i) { r0[i] = *(const bf8*)(v0 + i * 8);
                                      r1[i] = *(const bf8*)(v1 + i * 8); }
        #pragma unroll
        for (int d = 0; d < 32; ++d) {
            unsigned int w = ((unsigned int)(unsigned short)r0[d >> 3][d & 7]) |
                             (((unsigned int)(unsigned short)r1[d >> 3][d & 7]) << 16);
            *(unsigned int*)((char*)ldsVt + d * 1024 + ((4 * p) ^ ((d & 7) << 4))) = w;
        }
    }
    const int qoff = half * 256 + wid * 64;
    bf8 qf[2][2];
    #pragma unroll
    for (int qg = 0; qg < 2; ++qg)
        #pragma unroll
        for (int kh = 0; kh < 2; ++kh)
            qf[qg][kh] = *(const bf8*)(qkv + gbase +
                           (size_t)(qoff + qg * 32 + lq) * 384 + kh * 16 + lg * 8);
    __syncthreads();

    const f32x16 Z16 = {0.f,0.f,0.f,0.f,0.f,0.f,0.f,0.f,0.f,0.f,0.f,0.f,0.f,0.f,0.f,0.f};
    f32x16 o[2] = {Z16, Z16};
    float mreg[2] = {-1e30f, -1e30f};
    float lreg[2] = {0.f, 0.f};
    const bool hiw = (lg != 0);

    for (int kt = 0; kt < 16; ++kt) {
        bf8 ak[2], vt[2];
        #pragma unroll
        for (int kh = 0; kh < 2; ++kh) {
            ak[kh] = *(const bf8*)(ldsK + (kt * 32 + lq) * 40 + kh * 16 + lg * 8);
            int kbyte = (kt * 32 + kh * 16 + lg * 8) * 2;
            vt[kh] = *(const bf8*)((const char*)ldsVt + lq * 1024 +
                                   (kbyte ^ ((lq & 7) << 4)));
        }
        #pragma unroll
        for (int qg = 0; qg < 2; ++qg) {
            f32x16 s = Z16;
            s = __builtin_amdgcn_mfma_f32_32x32x16_bf16(ak[0], qf[qg][0], s, 0, 0, 0);
            s = __builtin_amdgcn_mfma_f32_32x32x16_bf16(ak[1], qf[qg][1], s, 0, 0, 0);
            float t0 = fmaxf(fmaxf(s[0],  s[1]),  s[2]);
            float t1 = fmaxf(fmaxf(s[3],  s[4]),  s[5]);
            float t2 = fmaxf(fmaxf(s[6],  s[7]),  s[8]);
            float t3 = fmaxf(fmaxf(s[9],  s[10]), s[11]);
            float t4 = fmaxf(fmaxf(s[12], s[13]), s[14]);
            float mt = fmaxf(fmaxf(fmaxf(t0, t1), t2), fmaxf(fmaxf(t3, t4), s[15]));
            mt = fmaxf(mt, __shfl_xor(mt, 32));
            if (__any(mt > mreg[qg] + 8.0f)) {       // defer-max (T13)
                float mnew = fmaxf(mreg[qg], mt);
                float corr = __expf(mreg[qg] - mnew);
                mreg[qg] = mnew;
                lreg[qg] *= corr;
                #pragma unroll
                for (int r = 0; r < 16; ++r) o[qg][r] *= corr;
            }
            float m = mreg[qg];
            float p[16]; float ps = 0.f;
            #pragma unroll
            for (int r = 0; r < 16; ++r) { p[r] = __expf(s[r] - m); ps += p[r]; }
            ps += __shfl_xor(ps, 32);
            lreg[qg] += ps;
            unsigned int w0 = pk2(p[0],  p[1]),  w1 = pk2(p[2],  p[3]);
            unsigned int w2 = pk2(p[4],  p[5]),  w3 = pk2(p[6],  p[7]);
            unsigned int w4 = pk2(p[8],  p[9]),  w5 = pk2(p[10], p[11]);
            unsigned int w6 = pk2(p[12], p[13]), w7 = pk2(p[14], p[15]);
            lswap(w0, w2, hiw); lswap(w1, w3, hiw);
            lswap(w4, w6, hiw); lswap(w5, w7, hiw);
            union { unsigned int u[4]; bf8 v; } P0, P1;
            P0.u[0] = w0; P0.u[1] = w1; P0.u[2] = w2; P0.u[3] = w3;
            P1.u[0] = w4; P1.u[1] = w5; P1.u[2] = w6; P1.u[3] = w7;
            o[qg] = __builtin_amdgcn_mfma_f32_32x32x16_bf16(vt[0], P0.v, o[qg], 0, 0, 0);
            o[qg] = __builtin_amdgcn_mfma_f32_32x32x16_bf16(vt[1], P1.v, o[qg], 0, 0, 0);
        }
    }

    __syncthreads();
    short* ldsO = ldsK;                    // [256 q][32 d], byte ^ ((q&7)<<3)
    #pragma unroll
    for (int qg = 0; qg < 2; ++qg) {
        float inv = 1.0f / lreg[qg];
        int ql = wid * 64 + qg * 32 + lq;
        #pragma unroll
        for (int b4 = 0; b4 < 4; ++b4) {
            short4 pkv;
            pkv.x = f2bs(o[qg][b4 * 4 + 0] * inv);
            pkv.y = f2bs(o[qg][b4 * 4 + 1] * inv);
            pkv.z = f2bs(o[qg][b4 * 4 + 2] * inv);
            pkv.w = f2bs(o[qg][b4 * 4 + 3] * inv);
            int dbyte = (8 * b4 + 4 * lg) * 2;
            *(short4*)((char*)ldsO + ql * 64 + (dbyte ^ ((ql & 7) << 3))) = pkv;
        }
    }
    __syncthreads();
    {
        int ql = tid;
        short* dst = ctx + (size_t)(b * 512 + half * 256 + ql) * 128 + h * 32;
        #pragma unroll
        for (int i = 0; i < 8; ++i) {
            short4 part = *(short4*)((char*)ldsO + ql * 64 + ((i * 8) ^ ((ql & 7) << 3)));
            *(short4*)(dst + i * 4) = part;
        }
    }
}

// ---------------------------------------------------------------------------
// k7: out_proj + combine: hbuf = hlocal + bn(hin1 + ctx@Wout^T + bout), bf16.
// ---------------------------------------------------------------------------
__global__ __launch_bounds__(256)
void outproj_combine_kernel(const short* __restrict__ ctxb, const short* __restrict__ wbf,
                            const float* __restrict__ bout,
                            const short* __restrict__ hin1b, const short* __restrict__ hlocb,
                            const float* __restrict__ gbn, const float* __restrict__ bbn,
                            short* __restrict__ hbufb)
{
    const int my = blockIdx.x;
    const int lane = threadIdx.x & 63;
    const int wid  = threadIdx.x >> 6;
    const int m0 = my * 64 + (wid >> 1) * 32;
    const int n0 = (wid & 1) * 64;
    const int lrow = lane & 15;
    const int lk   = (lane >> 4) * 8;
    const float rs = 0.9999950000374998f;

    f32x4 acc[2][4] = {};
    const short* Ap = ctxb + (size_t)(m0 + lrow) * 128 + lk;
    const short* Wp = wbf + 131072 + (size_t)(n0 + lrow) * 128 + lk;
    #pragma unroll
    for (int ks = 0; ks < 128; ks += 32) {
        bf8 af[2], wf[4];
        af[0] = *(const bf8*)(Ap + ks);
        af[1] = *(const bf8*)(Ap + 16 * 128 + ks);
        #pragma unroll
        for (int j = 0; j < 4; ++j) wf[j] = *(const bf8*)(Wp + (size_t)j * 16 * 128 + ks);
        #pragma unroll
        for (int i = 0; i < 2; ++i)
            #pragma unroll
            for (int j = 0; j < 4; ++j)
                acc[i][j] = __builtin_amdgcn_mfma_f32_16x16x32_bf16(af[i], wf[j], acc[i][j], 0, 0, 0);
    }
    const int rbase = (lane >> 4) * 4;
    #pragma unroll
    for (int j = 0; j < 4; ++j) {
        int col = n0 + j * 16 + lrow;
        float bcol = bout[col];
        float gsc = gbn[col] * rs;
        float bsc = bbn[col];
        #pragma unroll
        for (int i = 0; i < 2; ++i)
            #pragma unroll
            for (int r = 0; r < 4; ++r) {
                int row = m0 + i * 16 + rbase + r;
                size_t idx = (size_t)row * 128 + col;
                float v = acc[i][j][r] + bcol;
                float o = bs1f(hlocb[idx]) + (bs1f(hin1b[idx]) + v) * gsc + bsc;
                hbufb[idx] = f2bs(o);
            }
    }
}

// ---------------------------------------------------------------------------
// k8: fused FFN: ff1 = relu(hbuf@W1^T+b1) -> swizzled LDS; ff2 = ff1@W2^T+b2;
// out = bn(hbuf + ff2). One block per 64 rows.
// ---------------------------------------------------------------------------
__global__ __launch_bounds__(256)
void ff_fused_kernel(const short* __restrict__ hbufb, const short* __restrict__ wbf,
                     const float* __restrict__ b1, const float* __restrict__ b2,
                     const float* __restrict__ g2, const float* __restrict__ b2g,
                     float* __restrict__ out)
{
    __shared__ __align__(16) short ldsF[64 * 256];   // 32 KB
    const int my = blockIdx.x;
    const int lane = threadIdx.x & 63;
    const int wid  = threadIdx.x >> 6;
    const int lrow = lane & 15;
    const int lk   = (lane >> 4) * 8;
    const int rbase = (lane >> 4) * 4;
    const float rs = 0.9999950000374998f;

    // phase 1: ff1 tile 64x256 -> LDS (byte ^ ((row&7)<<4))
    {
        const int m0 = (wid >> 1) * 32;
        const int n0 = (wid & 1) * 128;
        f32x4 acc[2][8] = {};
        const short* Ap = hbufb + (size_t)(my * 64 + m0 + lrow) * 128 + lk;
        const short* Wp = wbf + 147456 + (size_t)(n0 + lrow) * 128 + lk;
        #pragma unroll
        for (int ks = 0; ks < 128; ks += 32) {
            bf8 af[2], wf[8];
            af[0] = *(const bf8*)(Ap + ks);
            af[1] = *(const bf8*)(Ap + 16 * 128 + ks);
            #pragma unroll
            for (int j = 0; j < 8; ++j) wf[j] = *(const bf8*)(Wp + (size_t)j * 16 * 128 + ks);
            #pragma unroll
            for (int i = 0; i < 2; ++i)
                #pragma unroll
                for (int j = 0; j < 8; ++j)
                    acc[i][j] = __builtin_amdgcn_mfma_f32_16x16x32_bf16(af[i], wf[j], acc[i][j], 0, 0, 0);
        }
        #pragma unroll
        for (int j = 0; j < 8; ++j) {
            int col = n0 + j * 16 + lrow;            // 0..255
            float bc = b1[col];
            #pragma unroll
            for (int i = 0; i < 2; ++i)
                #pragma unroll
                for (int r = 0; r < 4; ++r) {
                    int row = m0 + i * 16 + rbase + r;   // 0..63
                    float v = fmaxf(acc[i][j][r] + bc, 0.f);
                    int byte = (row * 512 + col * 2) ^ ((row & 7) << 4);
                    *(short*)((char*)ldsF + byte) = f2bs(v);
                }
        }
    }
    __syncthreads();
    // phase 2: ff2 + final BN
    {
        const int m0 = (wid >> 1) * 32;
        const int n0 = (wid & 1) * 64;
        f32x4 acc[2][4] = {};
        const short* Wp = wbf + 180224 + (size_t)(n0 + lrow) * 256 + lk;
        #pragma unroll
        for (int ks = 0; ks < 256; ks += 32) {
            bf8 af[2], wf[4];
            #pragma unroll
            for (int i = 0; i < 2; ++i) {
                int row = m0 + lrow + i * 16;
                int byte = (row * 512 + (ks + lk) * 2) ^ ((row & 7) << 4);
                af[i] = *(const bf8*)((const char*)ldsF + byte);
            }
            #pragma unroll
            for (int j = 0; j < 4; ++j) wf[j] = *(const bf8*)(Wp + (size_t)j * 16 * 256 + ks);
            #pragma unroll
            for (int i = 0; i < 2; ++i)
                #pragma unroll
                for (int j = 0; j < 4; ++j)
                    acc[i][j] = __builtin_amdgcn_mfma_f32_16x16x32_bf16(af[i], wf[j], acc[i][j], 0, 0, 0);
        }
        #pragma unroll
        for (int j = 0; j < 4; ++j) {
            int col = n0 + j * 16 + lrow;
            float bc = b2[col];
            float gsc = g2[col] * rs;
            float bsc = b2g[col];
            #pragma unroll
            for (int i = 0; i < 2; ++i)
                #pragma unroll
                for (int r = 0; r < 4; ++r) {
                    int row = my * 64 + m0 + i * 16 + rbase + r;
                    size_t idx = (size_t)row * 128 + col;
                    float v = acc[i][j][r] + bc;
                    out[idx] = (bs1f(hbufb[idx]) + v) * gsc + bsc;
                }
        }
    }
}

// ---------------------------------------------------------------------------
extern "C" void kernel_launch(void* const* d_in, const int* in_sizes, int n_in,
                              void* d_out, int out_size, void* d_ws, size_t ws_size,
                              hipStream_t stream)
{
    (void)in_sizes; (void)n_in; (void)out_size; (void)ws_size;

    const float* x    = (const float*)d_in[0];
    const int*   ei   = (const int*)d_in[1];
    const float* Wres = (const float*)d_in[3];
    const float* bres = (const float*)d_in[4];
    const float* Wk   = (const float*)d_in[5];
    const float* bk   = (const float*)d_in[6];
    const float* Wq   = (const float*)d_in[7];
    const float* bq   = (const float*)d_in[8];
    const float* Wv   = (const float*)d_in[9];
    const float* bv   = (const float*)d_in[10];
    const float* Wsk  = (const float*)d_in[11];
    const float* bsk  = (const float*)d_in[12];
    const float* g1l  = (const float*)d_in[13];
    const float* b1l  = (const float*)d_in[14];
    const float* g1a  = (const float*)d_in[15];
    const float* b1a  = (const float*)d_in[16];
    const float* Win  = (const float*)d_in[17];
    const float* bin  = (const float*)d_in[18];
    const float* Wout = (const float*)d_in[19];
    const float* bout = (const float*)d_in[20];
    const float* W1   = (const float*)d_in[21];
    const float* b1   = (const float*)d_in[22];
    const float* W2   = (const float*)d_in[23];
    const float* b2   = (const float*)d_in[24];
    const float* g2   = (const float*)d_in[25];
    const float* b2g  = (const float*)d_in[26];
    float* out = (float*)d_out;

    float* ws = (float*)d_ws;
    // ----- workspace layout (float-slot offsets), lifetimes k1..k8 -----
    short* hin1b = (short*)ws;                        // [0,0.5NM)  w:k2 r:k4,k5,k7
    short* kbv   = (short*)(ws + NM / 2);             // [0.5NM,NM) w:k2 r:k5
    short* qvb   = (short*)(ws + NM);                 // [NM,2NM)   w:k2 r:k5 (q,v ilv)
    short* skipb = (short*)(ws + 2 * NM);             // [2NM,2.5NM) w:k2 r:k5
    short* xb    = (short*)(ws + 2 * NM + NM / 2);    // [2.5NM,3NM) w:k1 r:k2
    short* qkvb  = (short*)(ws + 3 * NM);             // [3NM,4.5NM) w:k4 r:k6
    short* hlocb = (short*)(ws + 4 * NM + NM / 2);    // [4.5NM,5NM) w:k5 r:k7
    // CSR ints overlay [5NM, 5NM+622593) — dead after k5; ctxb (w:k6) reuses it
    int* deg     = (int*)(ws + 5 * NM);               // w:k1(zero),k2(hist) r:k3
    int* offsets = deg + N_NODES;                     // w:k3 r:k5
    int* cursor  = offsets + N_NODES + 1;             // w:k3 rmw:k4
    int* csr_src = cursor + N_NODES;                  // w:k4 r:k5
    short* ctxb  = (short*)(ws + 5 * NM);             // [5NM,5.5NM) w:k6 r:k7
    short* hbufb = (short*)(ws + 5 * NM + NM / 2);    // [5.5NM,6NM) w:k7 r:k8
    short* wbf   = (short*)(ws + 6 * NM);             // 212992 shorts = 106496 fslots
    float* bcat  = ws + 6 * NM + 106496;              // [640] f32
    // total extent: 6NM + 107136 floats ≈ 101.1 MB

    dim3 blk(256);
    const float qscale = 0.17677669529663687f;    // 1/sqrt(32)

    // 1. cvt + zero deg
    cvt_zero_kernel<<<dim3(4337), blk, 0, stream>>>(
        x, Wres, Wk, Wq, Wv, Wsk, Win, Wout, W1, W2,
        bres, bk, bq, bv, bsk, xb, wbf, bcat, deg);

    // 2. proj5 GEMM + hist
    proj5_hist_kernel<<<dim3(4608), blk, 0, stream>>>(
        xb, wbf, bcat, ei, hin1b, kbv, qvb, skipb, deg);

    // 3. scan
    scan_kernel<<<dim3(1), dim3(1024), 0, stream>>>(deg, offsets, cursor);

    // 4. in_proj GEMM + scatter
    inproj_scatter_kernel<<<dim3(3584), blk, 0, stream>>>(
        hin1b, wbf, bin, ei, cursor, csr_src, qkvb, qscale);

    // 5. gather + skip + BN
    gather_local_kernel<<<dim3(N_NODES / 4), blk, 0, stream>>>(
        (const unsigned int*)kbv, (const uint2*)qvb, (const unsigned int*)skipb,
        (const unsigned int*)hin1b, offsets, csr_src, g1l, b1l,
        (unsigned int*)hlocb);

    // 6. attention
    attn_mfma<<<dim3(512), blk, 0, stream>>>(qkvb, ctxb);

    // 7. out_proj + combine
    outproj_combine_kernel<<<dim3(512), blk, 0, stream>>>(
        ctxb, wbf, bout, hin1b, hlocb, g1a, b1a, hbufb);

    // 8. fused FFN + final BN
    ff_fused_kernel<<<dim3(512), blk, 0, stream>>>(
        hbufb, wbf, b1, b2, g2, b2g, out);
}